// Round 8
// baseline (643.272 us; speedup 1.0000x reference)
//
#include <hip/hip_runtime.h>
#include <cstddef>
#include <cstdint>

// B=8, C=2, Hf=257, T=2048, D_IN=514, DM=256, NL=4, N=32
// Activations: fp32 planes (b, 2*DM=512, T). GEMMs run bf16 MFMA.
// R8: mgemmln t-tile 64 -> 32 (grid 512 blocks = 2/CU co-resident) so the
// stage/epilogue memory phases of one block overlap the K-loop of the other.

typedef __attribute__((ext_vector_type(8))) short short8;
typedef __attribute__((ext_vector_type(4))) float float4v;

__device__ __forceinline__ unsigned short f2bf(float f) {
    union { float f; unsigned u; } v; v.f = f;
    const unsigned r = v.u + 0x7fffu + ((v.u >> 16) & 1u);  // RNE
    return (unsigned short)(r >> 16);
}

__device__ __forceinline__ float gelu_tanh(float x) {
    const float x3 = x * x * x;
    const float v  = 0.7978845608028654f * (x + 0.044715f * x3);
    const float e  = __expf(2.f * v);
    const float th = 1.f - 2.f / (e + 1.f);
    return 0.5f * x * (1.f + th);
}

// quad-perm DPP add: returns x + x[lane ^ k] for k in {1,2} (pure VALU).
template<int CTL>
__device__ __forceinline__ float dppadd(float x) {
    union { float f; int i; } a, r;
    a.f = x;
    r.i = __builtin_amdgcn_update_dpp(a.i, a.i, CTL, 0xF, 0xF, true);
    return x + r.f;
}
#define DPP_XOR1 0xB1  // quad_perm [1,0,3,2]
#define DPP_XOR2 0x4E  // quad_perm [2,3,0,1]

#define ASYNC_COPY16(gp, lp) __builtin_amdgcn_global_load_lds( \
    (const __attribute__((address_space(1))) unsigned int*)(gp), \
    (__attribute__((address_space(3))) unsigned int*)(lp), 16, 0, 0)

// ---------- ONE builder launch for all weights/biases ----------
// regions (256-thread blocks): [0,2112) enc W; [2112,6208) layer W (1024/l);
// [6208,8512) dec W (interleaved rows); [8512,8514) enc bias;
// [8514,8522) layer bias (2/l); [8522,8527) dec bias (interleaved).
__global__ __launch_bounds__(256) void buildall_k(
    const float* __restrict__ enc_Wr, const float* __restrict__ enc_Wi,
    const float* __restrict__ out_Wr, const float* __restrict__ out_Wi,
    const float* __restrict__ dec_Wr, const float* __restrict__ dec_Wi,
    const float* __restrict__ enc_br, const float* __restrict__ enc_bi,
    const float* __restrict__ out_br, const float* __restrict__ out_bi,
    const float* __restrict__ dec_br, const float* __restrict__ dec_bi,
    unsigned short* __restrict__ A_enc, unsigned short* __restrict__ A_lay,
    unsigned short* __restrict__ A_dec,
    float* __restrict__ b_enc, float* __restrict__ b_lay,
    float* __restrict__ b_dec)
{
    int blk = blockIdx.x;
    const int tid = threadIdx.x;
    if (blk < 2112) {
        // encoder W: G=256,H=514,Hoff=528,Kp=1056,Mp=512 (grid exact)
        const int i = blk * 256 + tid;
        const int m = i / 1056, k = i - m * 1056;
        const int ri = m >= 256, g = m & 255;
        const int blk2 = k >= 528;
        const int hh = k - blk2 * 528;
        float val = 0.f;
        if (hh < 514) {
            const float wr = enc_Wr[(size_t)g * 514 + hh];
            const float wi = enc_Wi[(size_t)g * 514 + hh];
            val = ri ? (blk2 ? wr : wi) : (blk2 ? -wi : wr);
        }
        A_enc[i] = f2bf(val);
        return;
    }
    blk -= 2112;
    if (blk < 4096) {
        // layer W: 4 layers, G=H=Hoff=256, Kp=Mp=512
        const int l = blk >> 10;
        const int i = ((blk & 1023) << 8) + tid;
        const float* Wr = out_Wr + (size_t)l * 65536;
        const float* Wi = out_Wi + (size_t)l * 65536;
        const int m = i >> 9, k = i & 511;
        const int ri = m >= 256, g = m & 255;
        const int blk2 = k >> 8, hh = k & 255;
        const float wr = Wr[(size_t)g * 256 + hh];
        const float wi = Wi[(size_t)g * 256 + hh];
        A_lay[(size_t)l * 262144 + i] =
            f2bf(ri ? (blk2 ? wr : wi) : (blk2 ? -wi : wr));
        return;
    }
    blk -= 4096;
    if (blk < 2304) {
        // decoder W, INTERLEAVED rows: m' -> (g = m'>>1, comp = m'&1).
        const int i = blk * 256 + tid;
        const int m = i >> 9, k = i & 511;
        const int g = m >> 1, comp = m & 1;
        float val = 0.f;
        if (g < 514) {
            const int blk2 = k >> 8, hh = k & 255;
            const float wr = dec_Wr[(size_t)g * 256 + hh];
            const float wi = dec_Wi[(size_t)g * 256 + hh];
            val = comp ? (blk2 ? wr : wi) : (blk2 ? -wi : wr);
        }
        A_dec[i] = f2bf(val);
        return;
    }
    blk -= 2304;
    if (blk < 2) {
        const int i = blk * 256 + tid;
        b_enc[i] = (i < 256) ? enc_br[i] : enc_bi[i - 256];
        return;
    }
    blk -= 2;
    if (blk < 8) {
        const int l = blk >> 1;
        const int i = ((blk & 1) << 8) + tid;
        b_lay[l * 512 + i] = (i < 256) ? out_br[l * 256 + i]
                                       : out_bi[l * 256 + i - 256];
        return;
    }
    blk -= 8;
    {
        // decoder bias, interleaved: b_dec[m'] for m' < 1028
        const int i = blk * 256 + tid;
        if (i < 1028) b_dec[i] = (i & 1) ? dec_bi[i >> 1] : dec_br[i >> 1];
    }
}

// ---------- encoder input pack: x (b,514,T,2) fp32 -> xp (b,T,1056) bf16 ----------
__global__ __launch_bounds__(256) void packx_k(const float* __restrict__ x,
                                               unsigned short* __restrict__ xp)
{
    const int t0 = blockIdx.x * 64, d0 = blockIdx.y * 64, b = blockIdx.z;
    __shared__ unsigned short tr_[64][72];
    __shared__ unsigned short ti_[64][72];
    const int tid = threadIdx.x;
    const int tp = tid & 31, dl0 = tid >> 5;
#pragma unroll
    for (int p = 0; p < 8; ++p) {
        const int d = dl0 + p * 8;
        const int gd = d0 + d;
        float4 v = make_float4(0.f, 0.f, 0.f, 0.f);
        if (gd < 514) v = *(const float4*)(x + (((size_t)b * 514 + gd) * 2048 + t0 + tp * 2) * 2);
        tr_[tp * 2 + 0][d] = f2bf(v.x); ti_[tp * 2 + 0][d] = f2bf(v.y);
        tr_[tp * 2 + 1][d] = f2bf(v.z); ti_[tp * 2 + 1][d] = f2bf(v.w);
    }
    __syncthreads();
    const int dc = tid & 7;
    const int kloc = d0 + dc * 8;
    if (kloc < 528) {
#pragma unroll
        for (int p = 0; p < 2; ++p) {
            const int t = (tid >> 3) + p * 32;
            const size_t rowb = ((size_t)b * 2048 + t0 + t) * 1056;
            *(short8*)&xp[rowb + kloc]       = *(const short8*)&tr_[t][dc * 8];
            *(short8*)&xp[rowb + 528 + kloc] = *(const short8*)&ti_[t][dc * 8];
        }
    }
}

// ---------- bf16 MFMA GEMM (encoder): out(b,M,T) = A * Bm^T + bias ----------
__global__ __launch_bounds__(256, 2) void mgemm_k(
    const unsigned short* __restrict__ A, const float* __restrict__ bias,
    const unsigned short* __restrict__ Bm, float* __restrict__ out,
    int M, int Kp)
{
    __shared__ unsigned short As[4096];  // [m 0..127][k 0..31]
    __shared__ unsigned short Bs[4096];  // [t 0..127][k 0..31]
    const int tid = threadIdx.x;
    const int w = tid >> 6, lane = tid & 63;
    const int m0 = blockIdx.x * 128, t0 = blockIdx.y * 128, b = blockIdx.z;
    const int wm = w & 1, wn = w >> 1;

    const unsigned short* Ab = A + (size_t)m0 * Kp;
    const unsigned short* Bb = Bm + ((size_t)b * 2048 + t0) * Kp;

    const int c0 = w * 64 + lane;
    const int r0 = c0 >> 2, q0 = (c0 & 3) * 8;
    const int c1 = c0 + 256;
    const int r1 = c1 >> 2, q1 = (c1 & 3) * 8;
    unsigned short* As0 = &As[(size_t)(w * 64) * 8];
    unsigned short* As1 = &As[(size_t)(w * 64 + 256) * 8];
    unsigned short* Bs0 = &Bs[(size_t)(w * 64) * 8];
    unsigned short* Bs1 = &Bs[(size_t)(w * 64 + 256) * 8];

    float4v acc[4][4];
#pragma unroll
    for (int i = 0; i < 4; ++i)
#pragma unroll
        for (int j = 0; j < 4; ++j) acc[i][j] = (float4v){0.f, 0.f, 0.f, 0.f};

    const int arow = wm * 64 + (lane & 15);
    const int brow = wn * 64 + (lane & 15);
    const int kq = (lane >> 4) * 8;

    for (int k0 = 0; k0 < Kp; k0 += 32) {
        ASYNC_COPY16(Ab + (size_t)r0 * Kp + k0 + q0, As0);
        ASYNC_COPY16(Ab + (size_t)r1 * Kp + k0 + q1, As1);
        ASYNC_COPY16(Bb + (size_t)r0 * Kp + k0 + q0, Bs0);
        ASYNC_COPY16(Bb + (size_t)r1 * Kp + k0 + q1, Bs1);
        __syncthreads();
        short8 af[4], bf[4];
#pragma unroll
        for (int i = 0; i < 4; ++i) af[i] = *(const short8*)&As[(arow + i * 16) * 32 + kq];
#pragma unroll
        for (int j = 0; j < 4; ++j) bf[j] = *(const short8*)&Bs[(brow + j * 16) * 32 + kq];
#pragma unroll
        for (int i = 0; i < 4; ++i)
#pragma unroll
            for (int j = 0; j < 4; ++j)
                acc[i][j] = __builtin_amdgcn_mfma_f32_16x16x32_bf16(af[i], bf[j], acc[i][j], 0, 0, 0);
        __syncthreads();
    }

    const int col = lane & 15;
    const int rq = (lane >> 4) * 4;
#pragma unroll
    for (int i = 0; i < 4; ++i) {
        const int mloc = wm * 64 + i * 16 + rq;
#pragma unroll
        for (int r = 0; r < 4; ++r) {
            const int m = m0 + mloc + r;
            const float bs = bias[m];
#pragma unroll
            for (int j = 0; j < 4; ++j) {
                const int t = t0 + wn * 64 + j * 16 + col;
                out[((size_t)b * 512 + m) * 2048 + t] = acc[i][j][r] + bs;
            }
        }
    }
}

// ---------- fused layer GEMM + residual + channel LayerNorm ----------
// R8: 32-t tiles (Bs 32KB), grid (64,8) = 512 blocks = 2/CU co-resident so
// one block's K-loop overlaps the other's stage/epilogue memory phases.
// B staged directly from t-major y planes (transpose on the LDS write),
// XOR swizzle mask(t) = ((t&7)^((t>>3)&7))<<4 (verified R5).
__global__ __launch_bounds__(512, 2) void mgemmln_k(
    const unsigned short* __restrict__ A, const float* __restrict__ bias,
    const unsigned short* __restrict__ Bm, float* __restrict__ z,
    const float* __restrict__ gamr, const float* __restrict__ gami,
    const float* __restrict__ betr, const float* __restrict__ beti, int l)
{
    __shared__ unsigned short Bs[32][512];   // 32KB, swizzled
    __shared__ float biasS[512], gamS[512], betS[512];
    __shared__ float sred[8][32][2];
    __shared__ float sstat[2][32][2];
    const int tid = threadIdx.x;
    const int w = tid >> 6, lane = tid & 63;
    const int t0g = blockIdx.x * 32, b = blockIdx.y;
    unsigned char* BsB = (unsigned char*)&Bs[0][0];

    // ---- stage B from y planes, transpose-on-write ----
    {
        const unsigned short* ysrc = Bm + (size_t)b * 512 * 2048 + t0g;
        const int tseg = lane & 3;       // 4 segs of 8 t
        const int rloc = lane >> 2;      // 16 rows per wave per p
#pragma unroll
        for (int p = 0; p < 4; ++p) {
            const int krow = w * 16 + rloc + p * 128;
            const short8 v = *(const short8*)(ysrc + (size_t)krow * 2048 + tseg * 8);
#pragma unroll
            for (int j = 0; j < 8; ++j) {
                const int t = tseg * 8 + j;
                const int mask = (((t & 7) ^ ((t >> 3) & 7)) << 4);
                *(unsigned short*)(BsB + t * 1024 + ((krow * 2) ^ mask)) =
                    ((const unsigned short*)&v)[j];
            }
        }
        const int m = tid, g = m & 255, comp = m >> 8;
        biasS[m] = bias[m];
        gamS[m] = (comp ? gami : gamr)[l * 256 + g];
        betS[m] = (comp ? beti : betr)[l * 256 + g];
    }
    __syncthreads();

    // ---- K-loop: A direct from global (L2-resident), B from LDS ----
    float4v acc[4][2];
#pragma unroll
    for (int i = 0; i < 4; ++i)
#pragma unroll
        for (int j = 0; j < 2; ++j) acc[i][j] = (float4v){0.f, 0.f, 0.f, 0.f};

    const int brow = lane & 15;
    const int kq8 = (lane >> 4) * 8;
    const unsigned short* Ab = A + ((size_t)(w * 64 + brow)) * 512 + kq8;
    int baseB[2], maskB[2];
#pragma unroll
    for (int j = 0; j < 2; ++j) {
        const int t = j * 16 + brow;
        baseB[j] = t * 1024;
        maskB[j] = (((t & 7) ^ ((t >> 3) & 7)) << 4);
    }

#define LOADF(af_, bf_, k0_) do {                                              \
    _Pragma("unroll")                                                          \
    for (int i = 0; i < 4; ++i)                                                \
        af_[i] = *(const short8*)(Ab + (size_t)i * 16 * 512 + (k0_));          \
    _Pragma("unroll")                                                          \
    for (int j = 0; j < 2; ++j)                                                \
        bf_[j] = *(const short8*)(BsB + baseB[j] + ((((k0_) + kq8) * 2) ^ maskB[j])); \
} while (0)
#define MFMAS(af_, bf_) do {                                                   \
    _Pragma("unroll")                                                          \
    for (int i = 0; i < 4; ++i)                                                \
        _Pragma("unroll")                                                      \
        for (int j = 0; j < 2; ++j)                                            \
            acc[i][j] = __builtin_amdgcn_mfma_f32_16x16x32_bf16(af_[i], bf_[j], acc[i][j], 0, 0, 0); \
} while (0)

    {
        short8 afA[4], bfA[2], afB[4], bfB[2];
        LOADF(afA, bfA, 0);
#pragma unroll 1
        for (int kk = 0; kk < 16; kk += 2) {
            LOADF(afB, bfB, kk * 32 + 32);
            MFMAS(afA, bfA);
            if (kk + 2 < 16) LOADF(afA, bfA, kk * 32 + 64);
            MFMAS(afB, bfB);
        }
    }
#undef LOADF
#undef MFMAS

    // ---- epilogue: v = acc + bias + z_old, LN stats, normalize, write z ----
    const int q4 = (lane >> 4) * 4;
    float4 b4[4], g4[4], e4[4];
#pragma unroll
    for (int i = 0; i < 4; ++i) {
        const int m0 = w * 64 + i * 16 + q4;
        b4[i] = *(const float4*)&biasS[m0];
        g4[i] = *(const float4*)&gamS[m0];
        e4[i] = *(const float4*)&betS[m0];
    }

    float s1[2], s2[2];
#pragma unroll
    for (int j = 0; j < 2; ++j) { s1[j] = 0.f; s2[j] = 0.f; }
#pragma unroll
    for (int j = 0; j < 2; ++j) {
        const int t = t0g + j * 16 + brow;
#pragma unroll
        for (int i = 0; i < 4; ++i) {
            const int m = w * 64 + i * 16 + q4;
            const float* zp = &z[((size_t)b * 512 + m) * 2048 + t];
            const float bb[4] = {b4[i].x, b4[i].y, b4[i].z, b4[i].w};
#pragma unroll
            for (int r = 0; r < 4; ++r) {
                const float v = acc[i][j][r] + bb[r] + zp[(size_t)r * 2048];
                acc[i][j][r] = v;
                s1[j] += v; s2[j] += v * v;
            }
        }
    }
#pragma unroll
    for (int j = 0; j < 2; ++j) {
        s1[j] += __shfl_xor(s1[j], 16); s2[j] += __shfl_xor(s2[j], 16);
        s1[j] += __shfl_xor(s1[j], 32); s2[j] += __shfl_xor(s2[j], 32);
    }
    if (lane < 16) {
#pragma unroll
        for (int j = 0; j < 2; ++j) {
            sred[w][j * 16 + lane][0] = s1[j];
            sred[w][j * 16 + lane][1] = s2[j];
        }
    }
    __syncthreads();
    if (tid < 64) {
        const int t = tid & 31, comp = tid >> 5;
        float S1 = 0.f, S2 = 0.f;
#pragma unroll
        for (int w2 = 0; w2 < 4; ++w2) {
            S1 += sred[comp * 4 + w2][t][0];
            S2 += sred[comp * 4 + w2][t][1];
        }
        const float mn = S1 * (1.f / 256.f);
        const float var = S2 * (1.f / 256.f) - mn * mn;
        sstat[comp][t][0] = mn;
        sstat[comp][t][1] = rsqrtf(var + 1e-5f);
    }
    __syncthreads();
    const int comp = w >> 2;
#pragma unroll
    for (int j = 0; j < 2; ++j) {
        const int tl = j * 16 + brow;
        const float mn = sstat[comp][tl][0], rs = sstat[comp][tl][1];
        const int t = t0g + tl;
#pragma unroll
        for (int i = 0; i < 4; ++i) {
            const int m = w * 64 + i * 16 + q4;
            float* zp = &z[((size_t)b * 512 + m) * 2048 + t];
            const float gg[4] = {g4[i].x, g4[i].y, g4[i].z, g4[i].w};
            const float ee[4] = {e4[i].x, e4[i].y, e4[i].z, e4[i].w};
#pragma unroll
            for (int r = 0; r < 4; ++r)
                zp[(size_t)r * 2048] = (acc[i][j][r] - mn) * rs * gg[r] + ee[r];
        }
    }
}

// ---------- fused decoder: transpose+convert z in-stage, GEMM, paired out ----------
// R7 (verified): A rows interleaved (m' -> g=m'>>1, comp=m'&1) -> float2
// {re,im} full-line stores.
__global__ __launch_bounds__(512, 2) void mgemmdec_k(
    const unsigned short* __restrict__ A, const float* __restrict__ bias,
    const float* __restrict__ z, float* __restrict__ out)
{
    __shared__ unsigned short Bs[64][512];   // 64KB, swizzled
    const int tid = threadIdx.x;
    const int w = tid >> 6, lane = tid & 63;
    const int m0b = blockIdx.x * 384;
    const int t0g = blockIdx.y * 64, b = blockIdx.z;
    unsigned char* BsB = (unsigned char*)&Bs[0][0];

    // ---- stage B from z fp32 planes: f2bf + transpose-on-write ----
    {
        const float* zsrc = z + (size_t)b * 512 * 2048 + t0g;
        const int tseg = lane & 7, rloc = lane >> 3;
#pragma unroll
        for (int p = 0; p < 8; ++p) {
            const int krow = w * 8 + rloc + p * 64;
            const float* rowp = zsrc + (size_t)krow * 2048 + tseg * 8;
            const float4 va = *(const float4*)rowp;
            const float4 vb = *(const float4*)(rowp + 4);
            const float vals[8] = {va.x, va.y, va.z, va.w, vb.x, vb.y, vb.z, vb.w};
#pragma unroll
            for (int j = 0; j < 8; ++j) {
                const int t = tseg * 8 + j;
                const int mask = (((t & 7) ^ ((t >> 3) & 7)) << 4);
                *(unsigned short*)(BsB + t * 1024 + ((krow * 2) ^ mask)) = f2bf(vals[j]);
            }
        }
    }
    __syncthreads();

    // ---- K-loop: A direct from global, B from LDS ----
    float4v acc[3][4];
#pragma unroll
    for (int i = 0; i < 3; ++i)
#pragma unroll
        for (int j = 0; j < 4; ++j) acc[i][j] = (float4v){0.f, 0.f, 0.f, 0.f};

    const int brow = lane & 15;
    const int kq8 = (lane >> 4) * 8;
    const unsigned short* Ab = A + ((size_t)(m0b + w * 48 + brow)) * 512 + kq8;
    int baseB[4], maskB[4];
#pragma unroll
    for (int j = 0; j < 4; ++j) {
        const int t = j * 16 + brow;
        baseB[j] = t * 1024;
        maskB[j] = (((t & 7) ^ ((t >> 3) & 7)) << 4);
    }

#define LOADF(af_, bf_, k0_) do {                                              \
    _Pragma("unroll")                                                          \
    for (int i = 0; i < 3; ++i)                                                \
        af_[i] = *(const short8*)(Ab + (size_t)i * 16 * 512 + (k0_));          \
    _Pragma("unroll")                                                          \
    for (int j = 0; j < 4; ++j)                                                \
        bf_[j] = *(const short8*)(BsB + baseB[j] + ((((k0_) + kq8) * 2) ^ maskB[j])); \
} while (0)
#define MFMAS(af_, bf_) do {                                                   \
    _Pragma("unroll")                                                          \
    for (int i = 0; i < 3; ++i)                                                \
        _Pragma("unroll")                                                      \
        for (int j = 0; j < 4; ++j)                                            \
            acc[i][j] = __builtin_amdgcn_mfma_f32_16x16x32_bf16(af_[i], bf_[j], acc[i][j], 0, 0, 0); \
} while (0)

    {
        short8 afA[3], bfA[4], afB[3], bfB[4];
        LOADF(afA, bfA, 0);
#pragma unroll 1
        for (int kk = 0; kk < 16; kk += 2) {
            LOADF(afB, bfB, kk * 32 + 32);
            MFMAS(afA, bfA);
            if (kk + 2 < 16) LOADF(afA, bfA, kk * 32 + 64);
            MFMAS(afB, bfB);
        }
    }
#undef LOADF
#undef MFMAS

    // ---- epilogue: bias + paired float2 stores (g<514 guard) ----
    const int q4 = (lane >> 4) * 4;
#pragma unroll
    for (int i = 0; i < 3; ++i) {
        const int mb = m0b + w * 48 + i * 16 + q4;   // even
#pragma unroll
        for (int pr = 0; pr < 2; ++pr) {
            const int m2 = mb + pr * 2;              // even row of the pair
            const int g = m2 >> 1;
            if (g >= 514) continue;
            const float br = bias[m2], bi2 = bias[m2 + 1];
            float* op = out + (((size_t)b * 514 + g) * 2048 + t0g) * 2;
#pragma unroll
            for (int j = 0; j < 4; ++j) {
                const int tl = j * 16 + brow;
                const float2 v = make_float2(acc[i][j][pr * 2 + 0] + br,
                                             acc[i][j][pr * 2 + 1] + bi2);
                *(float2*)(op + (size_t)tl * 2) = v;
            }
        }
    }
}

// ---------- S4D diagonal SSM scan + D-skip + gelu -> bf16 planes ----------
// R3 design + R6 tweak (exclusive shift via store-to-lane+1 slot).
__global__ __launch_bounds__(256, 4) void s4scan_k(
    const float* __restrict__ z, unsigned short* __restrict__ y,
    const float* __restrict__ log_dt, const float* __restrict__ log_A_real,
    const float* __restrict__ A_imag, const float* __restrict__ C_r,
    const float* __restrict__ C_i, const float* __restrict__ Dsk, int l)
{
    const int h = blockIdx.x, b = blockIdx.y;
    const int tid = threadIdx.x;
    const int lane = tid & 63, wv = tid >> 6;
    __shared__ float2 wsh[32], csh[32];
    __shared__ float dsh;
    __shared__ float2 us[64][33];
    __shared__ __align__(16) unsigned char uni[64 * 33 * 8];
    float2 (*vsh2)[33] = (float2(*)[33])uni;
    float2 (*ys)[33]   = (float2(*)[33])uni;

    if (tid < 32) {
        const size_t pidx = ((size_t)l * 256 + h) * 32 + tid;
        const float dt = __expf(log_dt[l * 256 + h]);
        const float Ar = -__expf(log_A_real[pidx]);
        const float Ai = A_imag[pidx];
        const float er = __expf(Ar * dt);
        float sv, cv;
        __sincosf(Ai * dt, &sv, &cv);
        const float wr = er * cv, wi = er * sv;
        const float den = 1.f / (Ar * Ar + Ai * Ai);
        const float nr = wr - 1.f, ni = wi;
        const float qr = (nr * Ar + ni * Ai) * den;
        const float qi = (ni * Ar - nr * Ai) * den;
        const float cr = C_r[pidx], ci = C_i[pidx];
        wsh[tid] = make_float2(wr, wi);
        csh[tid] = make_float2(cr * qr - ci * qi, cr * qi + ci * qr);
    }
    if (tid == 32) dsh = Dsk[l * 256 + h];

    const int c0q = tid >> 2, t0q = (tid & 3) * 8;
    {
        const float* zrp = z + ((size_t)b * 512 + h) * 2048 + tid * 8;
        const float* zip = zrp + 256 * 2048;
        const float4 r0 = *(const float4*)zrp, r1 = *(const float4*)(zrp + 4);
        const float4 i0 = *(const float4*)zip, i1 = *(const float4*)(zip + 4);
        float2* up = &us[c0q][t0q];
        up[0] = make_float2(r0.x, i0.x); up[1] = make_float2(r0.y, i0.y);
        up[2] = make_float2(r0.z, i0.z); up[3] = make_float2(r0.w, i0.w);
        up[4] = make_float2(r1.x, i1.x); up[5] = make_float2(r1.y, i1.y);
        up[6] = make_float2(r1.z, i1.z); up[7] = make_float2(r1.w, i1.w);
    }
    __syncthreads();

    // ---- sweep 1: chunk-local finals + butterfly -> exclusive states ----
    {
        float2 w8[8], x8[8];
#pragma unroll
        for (int j = 0; j < 8; ++j) {
            w8[j] = wsh[wv * 8 + j];
            x8[j] = make_float2(0.f, 0.f);
        }
#pragma unroll 8
        for (int tt = 0; tt < 32; ++tt) {
            const float2 u = us[lane][tt];
#pragma unroll
            for (int j = 0; j < 8; ++j) {
                const float nxr = __builtin_fmaf(w8[j].x, x8[j].x, __builtin_fmaf(-w8[j].y, x8[j].y, u.x));
                const float nxi = __builtin_fmaf(w8[j].x, x8[j].y, __builtin_fmaf(w8[j].y, x8[j].x, u.y));
                x8[j].x = nxr; x8[j].y = nxi;
            }
        }
        const int dstc = (lane + 1) & 63;
#pragma unroll
        for (int j = 0; j < 8; ++j) {
            float fr = w8[j].x, fi = w8[j].y;
#pragma unroll
            for (int s = 0; s < 5; ++s) { const float a2 = fr * fr - fi * fi, b2 = 2.f * fr * fi; fr = a2; fi = b2; }
            float qrv = x8[j].x, qiv = x8[j].y, pr = fr, pi = fi;
#pragma unroll
            for (int s = 0; s < 6; ++s) {
                const int d = 1 << s;
                const float sr = __shfl_up(qrv, (unsigned)d);
                const float si = __shfl_up(qiv, (unsigned)d);
                if (lane >= d) {
                    qrv += pr * sr - pi * si;
                    qiv += pr * si + pi * sr;
                }
                const float a2 = pr * pr - pi * pi, b2 = 2.f * pr * pi;
                pr = a2; pi = b2;
            }
            vsh2[dstc][wv * 8 + j] = (lane == 63) ? make_float2(0.f, 0.f)
                                                  : make_float2(qrv, qiv);
        }
    }
    __syncthreads();

    // ---- sweep 2: single 8-mode pass, DPP reduce, ys written once ----
    {
        const int q = tid & 3;
        float2 w8[8], c8[8], s8[8];
#pragma unroll
        for (int j = 0; j < 8; ++j) {
            const int n = q * 8 + j;
            w8[j] = wsh[n];
            c8[j] = csh[n];
            s8[j] = vsh2[c0q][n];
        }
        __syncthreads();  // vsh2 fully in regs; ys may now overwrite it
#pragma unroll 4
        for (int tt = 0; tt < 32; ++tt) {
            const float2 u = us[c0q][tt];
            float pyr = 0.f, pyi = 0.f;
#pragma unroll
            for (int j = 0; j < 8; ++j) {
                const float nsr = __builtin_fmaf(w8[j].x, s8[j].x, __builtin_fmaf(-w8[j].y, s8[j].y, u.x));
                const float nsi = __builtin_fmaf(w8[j].x, s8[j].y, __builtin_fmaf(w8[j].y, s8[j].x, u.y));
                s8[j].x = nsr; s8[j].y = nsi;
                pyr = __builtin_fmaf(c8[j].x, nsr, __builtin_fmaf(-c8[j].y, nsi, pyr));
                pyi = __builtin_fmaf(c8[j].x, nsi, __builtin_fmaf(c8[j].y, nsr, pyi));
            }
            pyr = dppadd<DPP_XOR1>(pyr); pyr = dppadd<DPP_XOR2>(pyr);
            pyi = dppadd<DPP_XOR1>(pyi); pyi = dppadd<DPP_XOR2>(pyi);
            if (q == 0) ys[c0q][tt] = make_float2(pyr, pyi);
        }
    }
    __syncthreads();

    // ---- final: D-skip + gelu + bf16 pack + coalesced stores ----
    {
        const float dv = dsh;
        unsigned short* yrp = y + ((size_t)b * 512 + h) * 2048 + tid * 8;
        unsigned short* yip = yrp + 256 * 2048;
        short8 vr8, vi8;
#pragma unroll
        for (int j = 0; j < 8; ++j) {
            const float2 yv = ys[c0q][t0q + j];
            const float2 uv = us[c0q][t0q + j];
            ((unsigned short*)&vr8)[j] = f2bf(gelu_tanh(__builtin_fmaf(dv, uv.x, yv.x)));
            ((unsigned short*)&vi8)[j] = f2bf(gelu_tanh(__builtin_fmaf(dv, uv.y, yv.y)));
        }
        *(short8*)yrp = vr8;
        *(short8*)yip = vi8;
    }
}

extern "C" void kernel_launch(void* const* d_in, const int* in_sizes, int n_in,
                              void* d_out, int out_size, void* d_ws, size_t ws_size,
                              hipStream_t stream)
{
    const float* x        = (const float*)d_in[0];
    const float* enc_Wr   = (const float*)d_in[1];
    const float* enc_Wi   = (const float*)d_in[2];
    const float* enc_br   = (const float*)d_in[3];
    const float* enc_bi   = (const float*)d_in[4];
    const float* log_dt   = (const float*)d_in[5];
    const float* log_A_r  = (const float*)d_in[6];
    const float* A_imag   = (const float*)d_in[7];
    const float* C_r      = (const float*)d_in[8];
    const float* C_i      = (const float*)d_in[9];
    const float* Dp       = (const float*)d_in[10];
    const float* out_Wr   = (const float*)d_in[11];
    const float* out_Wi   = (const float*)d_in[12];
    const float* out_br   = (const float*)d_in[13];
    const float* out_bi   = (const float*)d_in[14];
    const float* ln_gr    = (const float*)d_in[15];
    const float* ln_gi    = (const float*)d_in[16];
    const float* ln_br    = (const float*)d_in[17];
    const float* ln_bi    = (const float*)d_in[18];
    const float* dec_Wr   = (const float*)d_in[19];
    const float* dec_Wi   = (const float*)d_in[20];
    const float* dec_br   = (const float*)d_in[21];
    const float* dec_bi   = (const float*)d_in[22];

    // ---- workspace layout (bytes) ----
    uint8_t* W = (uint8_t*)d_ws;
    float* z             = (float*)W;                       // 33,554,432
    unsigned short* A_enc= (unsigned short*)(W + 50331648); // 512x1056x2  = 1,081,344
    unsigned short* A_lay= (unsigned short*)(W + 51412992); // 4x512x512x2 = 2,097,152
    unsigned short* A_dec= (unsigned short*)(W + 53510144); // 1152x512x2  = 1,179,648
    float* b_enc         = (float*)(W + 54689792);          // 512 f
    float* b_lay         = (float*)(W + 54691840);          // 2048 f
    float* b_dec         = (float*)(W + 54700032);          // 1028 f

    // ---- d_out doubles as scratch ----
    unsigned short* y   = (unsigned short*)((uint8_t*)d_out + 33554432);   // 16,777,216
    unsigned short* xp  = (unsigned short*)d_out;  // 34,603,008; dead after encoder GEMM

    // ---- build all weights/biases in one launch ----
    buildall_k<<<8527, 256, 0, stream>>>(enc_Wr, enc_Wi, out_Wr, out_Wi,
                                         dec_Wr, dec_Wi, enc_br, enc_bi,
                                         out_br, out_bi, dec_br, dec_bi,
                                         A_enc, A_lay, A_dec,
                                         b_enc, b_lay, b_dec);

    // ---- encoder: pack x -> xp, GEMM -> z ----
    packx_k<<<dim3(32, 9, 8), 256, 0, stream>>>(x, xp);
    mgemm_k<<<dim3(4, 16, 8), 256, 0, stream>>>(A_enc, b_enc, xp, z, 512, 1056);

    // ---- layers: scan -> fused transpose+GEMM+residual+LN ----
    for (int l = 0; l < 4; ++l) {
        s4scan_k<<<dim3(256, 8), 256, 0, stream>>>(z, y, log_dt, log_A_r, A_imag, C_r, C_i, Dp, l);
        mgemmln_k<<<dim3(64, 8), 512, 0, stream>>>(A_lay + (size_t)l * 262144,
                                                   b_lay + l * 512, y, z,
                                                   ln_gr, ln_gi, ln_br, ln_bi, l);
    }

    // ---- decoder: fused transpose+convert+GEMM -> d_out paired stores ----
    mgemmdec_k<<<dim3(3, 32, 8), 512, 0, stream>>>(A_dec, b_dec, z, (float*)d_out);
}

// Round 9
// 588.437 us; speedup vs baseline: 1.0932x; 1.0932x over previous
//
#include <hip/hip_runtime.h>
#include <cstddef>
#include <cstdint>

// B=8, C=2, Hf=257, T=2048, D_IN=514, DM=256, NL=4, N=32
// Activations: fp32 planes (b, 2*DM=512, T). GEMMs run bf16 MFMA.
// R9: revert R8's 32-t mgemmln tile (regressed +54us: doubled A traffic +
// doubled per-tile fixed costs, no co-residency overlap materialized).
// Back to the verified R7 configuration: 64-t mgemmln, paired-store decoder,
// merged builder, R6 s4scan.

typedef __attribute__((ext_vector_type(8))) short short8;
typedef __attribute__((ext_vector_type(4))) float float4v;

__device__ __forceinline__ unsigned short f2bf(float f) {
    union { float f; unsigned u; } v; v.f = f;
    const unsigned r = v.u + 0x7fffu + ((v.u >> 16) & 1u);  // RNE
    return (unsigned short)(r >> 16);
}

__device__ __forceinline__ float gelu_tanh(float x) {
    const float x3 = x * x * x;
    const float v  = 0.7978845608028654f * (x + 0.044715f * x3);
    const float e  = __expf(2.f * v);
    const float th = 1.f - 2.f / (e + 1.f);
    return 0.5f * x * (1.f + th);
}

// quad-perm DPP add: returns x + x[lane ^ k] for k in {1,2} (pure VALU).
template<int CTL>
__device__ __forceinline__ float dppadd(float x) {
    union { float f; int i; } a, r;
    a.f = x;
    r.i = __builtin_amdgcn_update_dpp(a.i, a.i, CTL, 0xF, 0xF, true);
    return x + r.f;
}
#define DPP_XOR1 0xB1  // quad_perm [1,0,3,2]
#define DPP_XOR2 0x4E  // quad_perm [2,3,0,1]

#define ASYNC_COPY16(gp, lp) __builtin_amdgcn_global_load_lds( \
    (const __attribute__((address_space(1))) unsigned int*)(gp), \
    (__attribute__((address_space(3))) unsigned int*)(lp), 16, 0, 0)

// ---------- ONE builder launch for all weights/biases ----------
// regions (256-thread blocks): [0,2112) enc W; [2112,6208) layer W (1024/l);
// [6208,8512) dec W (interleaved rows); [8512,8514) enc bias;
// [8514,8522) layer bias (2/l); [8522,8527) dec bias (interleaved).
__global__ __launch_bounds__(256) void buildall_k(
    const float* __restrict__ enc_Wr, const float* __restrict__ enc_Wi,
    const float* __restrict__ out_Wr, const float* __restrict__ out_Wi,
    const float* __restrict__ dec_Wr, const float* __restrict__ dec_Wi,
    const float* __restrict__ enc_br, const float* __restrict__ enc_bi,
    const float* __restrict__ out_br, const float* __restrict__ out_bi,
    const float* __restrict__ dec_br, const float* __restrict__ dec_bi,
    unsigned short* __restrict__ A_enc, unsigned short* __restrict__ A_lay,
    unsigned short* __restrict__ A_dec,
    float* __restrict__ b_enc, float* __restrict__ b_lay,
    float* __restrict__ b_dec)
{
    int blk = blockIdx.x;
    const int tid = threadIdx.x;
    if (blk < 2112) {
        // encoder W: G=256,H=514,Hoff=528,Kp=1056,Mp=512 (grid exact)
        const int i = blk * 256 + tid;
        const int m = i / 1056, k = i - m * 1056;
        const int ri = m >= 256, g = m & 255;
        const int blk2 = k >= 528;
        const int hh = k - blk2 * 528;
        float val = 0.f;
        if (hh < 514) {
            const float wr = enc_Wr[(size_t)g * 514 + hh];
            const float wi = enc_Wi[(size_t)g * 514 + hh];
            val = ri ? (blk2 ? wr : wi) : (blk2 ? -wi : wr);
        }
        A_enc[i] = f2bf(val);
        return;
    }
    blk -= 2112;
    if (blk < 4096) {
        // layer W: 4 layers, G=H=Hoff=256, Kp=Mp=512
        const int l = blk >> 10;
        const int i = ((blk & 1023) << 8) + tid;
        const float* Wr = out_Wr + (size_t)l * 65536;
        const float* Wi = out_Wi + (size_t)l * 65536;
        const int m = i >> 9, k = i & 511;
        const int ri = m >= 256, g = m & 255;
        const int blk2 = k >> 8, hh = k & 255;
        const float wr = Wr[(size_t)g * 256 + hh];
        const float wi = Wi[(size_t)g * 256 + hh];
        A_lay[(size_t)l * 262144 + i] =
            f2bf(ri ? (blk2 ? wr : wi) : (blk2 ? -wi : wr));
        return;
    }
    blk -= 4096;
    if (blk < 2304) {
        // decoder W, INTERLEAVED rows: m' -> (g = m'>>1, comp = m'&1).
        const int i = blk * 256 + tid;
        const int m = i >> 9, k = i & 511;
        const int g = m >> 1, comp = m & 1;
        float val = 0.f;
        if (g < 514) {
            const int blk2 = k >> 8, hh = k & 255;
            const float wr = dec_Wr[(size_t)g * 256 + hh];
            const float wi = dec_Wi[(size_t)g * 256 + hh];
            val = comp ? (blk2 ? wr : wi) : (blk2 ? -wi : wr);
        }
        A_dec[i] = f2bf(val);
        return;
    }
    blk -= 2304;
    if (blk < 2) {
        const int i = blk * 256 + tid;
        b_enc[i] = (i < 256) ? enc_br[i] : enc_bi[i - 256];
        return;
    }
    blk -= 2;
    if (blk < 8) {
        const int l = blk >> 1;
        const int i = ((blk & 1) << 8) + tid;
        b_lay[l * 512 + i] = (i < 256) ? out_br[l * 256 + i]
                                       : out_bi[l * 256 + i - 256];
        return;
    }
    blk -= 8;
    {
        // decoder bias, interleaved: b_dec[m'] for m' < 1028
        const int i = blk * 256 + tid;
        if (i < 1028) b_dec[i] = (i & 1) ? dec_bi[i >> 1] : dec_br[i >> 1];
    }
}

// ---------- encoder input pack: x (b,514,T,2) fp32 -> xp (b,T,1056) bf16 ----------
__global__ __launch_bounds__(256) void packx_k(const float* __restrict__ x,
                                               unsigned short* __restrict__ xp)
{
    const int t0 = blockIdx.x * 64, d0 = blockIdx.y * 64, b = blockIdx.z;
    __shared__ unsigned short tr_[64][72];
    __shared__ unsigned short ti_[64][72];
    const int tid = threadIdx.x;
    const int tp = tid & 31, dl0 = tid >> 5;
#pragma unroll
    for (int p = 0; p < 8; ++p) {
        const int d = dl0 + p * 8;
        const int gd = d0 + d;
        float4 v = make_float4(0.f, 0.f, 0.f, 0.f);
        if (gd < 514) v = *(const float4*)(x + (((size_t)b * 514 + gd) * 2048 + t0 + tp * 2) * 2);
        tr_[tp * 2 + 0][d] = f2bf(v.x); ti_[tp * 2 + 0][d] = f2bf(v.y);
        tr_[tp * 2 + 1][d] = f2bf(v.z); ti_[tp * 2 + 1][d] = f2bf(v.w);
    }
    __syncthreads();
    const int dc = tid & 7;
    const int kloc = d0 + dc * 8;
    if (kloc < 528) {
#pragma unroll
        for (int p = 0; p < 2; ++p) {
            const int t = (tid >> 3) + p * 32;
            const size_t rowb = ((size_t)b * 2048 + t0 + t) * 1056;
            *(short8*)&xp[rowb + kloc]       = *(const short8*)&tr_[t][dc * 8];
            *(short8*)&xp[rowb + 528 + kloc] = *(const short8*)&ti_[t][dc * 8];
        }
    }
}

// ---------- bf16 MFMA GEMM (encoder): out(b,M,T) = A * Bm^T + bias ----------
__global__ __launch_bounds__(256, 2) void mgemm_k(
    const unsigned short* __restrict__ A, const float* __restrict__ bias,
    const unsigned short* __restrict__ Bm, float* __restrict__ out,
    int M, int Kp)
{
    __shared__ unsigned short As[4096];  // [m 0..127][k 0..31]
    __shared__ unsigned short Bs[4096];  // [t 0..127][k 0..31]
    const int tid = threadIdx.x;
    const int w = tid >> 6, lane = tid & 63;
    const int m0 = blockIdx.x * 128, t0 = blockIdx.y * 128, b = blockIdx.z;
    const int wm = w & 1, wn = w >> 1;

    const unsigned short* Ab = A + (size_t)m0 * Kp;
    const unsigned short* Bb = Bm + ((size_t)b * 2048 + t0) * Kp;

    const int c0 = w * 64 + lane;
    const int r0 = c0 >> 2, q0 = (c0 & 3) * 8;
    const int c1 = c0 + 256;
    const int r1 = c1 >> 2, q1 = (c1 & 3) * 8;
    unsigned short* As0 = &As[(size_t)(w * 64) * 8];
    unsigned short* As1 = &As[(size_t)(w * 64 + 256) * 8];
    unsigned short* Bs0 = &Bs[(size_t)(w * 64) * 8];
    unsigned short* Bs1 = &Bs[(size_t)(w * 64 + 256) * 8];

    float4v acc[4][4];
#pragma unroll
    for (int i = 0; i < 4; ++i)
#pragma unroll
        for (int j = 0; j < 4; ++j) acc[i][j] = (float4v){0.f, 0.f, 0.f, 0.f};

    const int arow = wm * 64 + (lane & 15);
    const int brow = wn * 64 + (lane & 15);
    const int kq = (lane >> 4) * 8;

    for (int k0 = 0; k0 < Kp; k0 += 32) {
        ASYNC_COPY16(Ab + (size_t)r0 * Kp + k0 + q0, As0);
        ASYNC_COPY16(Ab + (size_t)r1 * Kp + k0 + q1, As1);
        ASYNC_COPY16(Bb + (size_t)r0 * Kp + k0 + q0, Bs0);
        ASYNC_COPY16(Bb + (size_t)r1 * Kp + k0 + q1, Bs1);
        __syncthreads();
        short8 af[4], bf[4];
#pragma unroll
        for (int i = 0; i < 4; ++i) af[i] = *(const short8*)&As[(arow + i * 16) * 32 + kq];
#pragma unroll
        for (int j = 0; j < 4; ++j) bf[j] = *(const short8*)&Bs[(brow + j * 16) * 32 + kq];
#pragma unroll
        for (int i = 0; i < 4; ++i)
#pragma unroll
            for (int j = 0; j < 4; ++j)
                acc[i][j] = __builtin_amdgcn_mfma_f32_16x16x32_bf16(af[i], bf[j], acc[i][j], 0, 0, 0);
        __syncthreads();
    }

    const int col = lane & 15;
    const int rq = (lane >> 4) * 4;
#pragma unroll
    for (int i = 0; i < 4; ++i) {
        const int mloc = wm * 64 + i * 16 + rq;
#pragma unroll
        for (int r = 0; r < 4; ++r) {
            const int m = m0 + mloc + r;
            const float bs = bias[m];
#pragma unroll
            for (int j = 0; j < 4; ++j) {
                const int t = t0 + wn * 64 + j * 16 + col;
                out[((size_t)b * 512 + m) * 2048 + t] = acc[i][j][r] + bs;
            }
        }
    }
}

// ---------- fused layer GEMM + residual + channel LayerNorm ----------
// R7 verified optimum: 64-t tile, B staged directly from t-major y planes
// (transpose on the LDS write), XOR swizzle mask(t) = ((t&7)^((t>>3)&7))<<4.
// R8's 32-t variant regressed (doubled A traffic + per-tile fixed costs).
__global__ __launch_bounds__(512, 2) void mgemmln_k(
    const unsigned short* __restrict__ A, const float* __restrict__ bias,
    const unsigned short* __restrict__ Bm, float* __restrict__ z,
    const float* __restrict__ gamr, const float* __restrict__ gami,
    const float* __restrict__ betr, const float* __restrict__ beti, int l)
{
    __shared__ unsigned short Bs[64][512];   // 64KB, swizzled
    __shared__ float biasS[512], gamS[512], betS[512];
    __shared__ float sred[8][64][2];
    __shared__ float sstat[2][64][2];
    const int tid = threadIdx.x;
    const int w = tid >> 6, lane = tid & 63;
    const int t0g = blockIdx.x * 64, b = blockIdx.y;
    unsigned char* BsB = (unsigned char*)&Bs[0][0];

    // ---- stage B from y planes, transpose-on-write ----
    {
        const unsigned short* ysrc = Bm + (size_t)b * 512 * 2048 + t0g;
        const int tseg = lane & 7;       // 8-t segment (t = tseg*8 + j)
        const int rloc = lane >> 3;      // row within the wave's octet
#pragma unroll
        for (int p = 0; p < 8; ++p) {
            const int krow = w * 8 + rloc + p * 64;
            const short8 v = *(const short8*)(ysrc + (size_t)krow * 2048 + tseg * 8);
#pragma unroll
            for (int j = 0; j < 8; ++j) {
                const int t = tseg * 8 + j;
                const int mask = (((t & 7) ^ ((t >> 3) & 7)) << 4);
                *(unsigned short*)(BsB + t * 1024 + ((krow * 2) ^ mask)) =
                    ((const unsigned short*)&v)[j];
            }
        }
        const int m = tid, g = m & 255, comp = m >> 8;
        biasS[m] = bias[m];
        gamS[m] = (comp ? gami : gamr)[l * 256 + g];
        betS[m] = (comp ? beti : betr)[l * 256 + g];
    }
    __syncthreads();

    // ---- K-loop: A direct from global (L2-resident), B from LDS ----
    float4v acc[4][4];
#pragma unroll
    for (int i = 0; i < 4; ++i)
#pragma unroll
        for (int j = 0; j < 4; ++j) acc[i][j] = (float4v){0.f, 0.f, 0.f, 0.f};

    const int brow = lane & 15;
    const int kq8 = (lane >> 4) * 8;
    const unsigned short* Ab = A + ((size_t)(w * 64 + brow)) * 512 + kq8;
    int baseB[4], maskB[4];
#pragma unroll
    for (int j = 0; j < 4; ++j) {
        const int t = j * 16 + brow;
        baseB[j] = t * 1024;
        maskB[j] = (((t & 7) ^ ((t >> 3) & 7)) << 4);
    }

#define LOADF(af_, bf_, k0_) do {                                              \
    _Pragma("unroll")                                                          \
    for (int i = 0; i < 4; ++i)                                                \
        af_[i] = *(const short8*)(Ab + (size_t)i * 16 * 512 + (k0_));          \
    _Pragma("unroll")                                                          \
    for (int j = 0; j < 4; ++j)                                                \
        bf_[j] = *(const short8*)(BsB + baseB[j] + ((((k0_) + kq8) * 2) ^ maskB[j])); \
} while (0)
#define MFMAS(af_, bf_) do {                                                   \
    _Pragma("unroll")                                                          \
    for (int i = 0; i < 4; ++i)                                                \
        _Pragma("unroll")                                                      \
        for (int j = 0; j < 4; ++j)                                            \
            acc[i][j] = __builtin_amdgcn_mfma_f32_16x16x32_bf16(af_[i], bf_[j], acc[i][j], 0, 0, 0); \
} while (0)

    {
        short8 afA[4], bfA[4], afB[4], bfB[4];
        LOADF(afA, bfA, 0);
#pragma unroll 1
        for (int kk = 0; kk < 16; kk += 2) {
            LOADF(afB, bfB, kk * 32 + 32);
            MFMAS(afA, bfA);
            if (kk + 2 < 16) LOADF(afA, bfA, kk * 32 + 64);
            MFMAS(afB, bfB);
        }
    }
#undef LOADF
#undef MFMAS

    // ---- epilogue: v = acc + bias + z_old, LN stats, normalize, write z ----
    const int q4 = (lane >> 4) * 4;
    float4 b4[4], g4[4], e4[4];
#pragma unroll
    for (int i = 0; i < 4; ++i) {
        const int m0 = w * 64 + i * 16 + q4;
        b4[i] = *(const float4*)&biasS[m0];
        g4[i] = *(const float4*)&gamS[m0];
        e4[i] = *(const float4*)&betS[m0];
    }

    float s1[4], s2[4];
#pragma unroll
    for (int j = 0; j < 4; ++j) { s1[j] = 0.f; s2[j] = 0.f; }
#pragma unroll
    for (int j = 0; j < 4; ++j) {
        const int t = t0g + j * 16 + brow;
#pragma unroll
        for (int i = 0; i < 4; ++i) {
            const int m = w * 64 + i * 16 + q4;
            const float* zp = &z[((size_t)b * 512 + m) * 2048 + t];
            const float bb[4] = {b4[i].x, b4[i].y, b4[i].z, b4[i].w};
#pragma unroll
            for (int r = 0; r < 4; ++r) {
                const float v = acc[i][j][r] + bb[r] + zp[(size_t)r * 2048];
                acc[i][j][r] = v;
                s1[j] += v; s2[j] += v * v;
            }
        }
    }
#pragma unroll
    for (int j = 0; j < 4; ++j) {
        s1[j] += __shfl_xor(s1[j], 16); s2[j] += __shfl_xor(s2[j], 16);
        s1[j] += __shfl_xor(s1[j], 32); s2[j] += __shfl_xor(s2[j], 32);
    }
    if (lane < 16) {
#pragma unroll
        for (int j = 0; j < 4; ++j) {
            sred[w][j * 16 + lane][0] = s1[j];
            sred[w][j * 16 + lane][1] = s2[j];
        }
    }
    __syncthreads();
    if (tid < 128) {
        const int t = tid & 63, comp = tid >> 6;
        float S1 = 0.f, S2 = 0.f;
#pragma unroll
        for (int w2 = 0; w2 < 4; ++w2) {
            S1 += sred[comp * 4 + w2][t][0];
            S2 += sred[comp * 4 + w2][t][1];
        }
        const float mn = S1 * (1.f / 256.f);
        const float var = S2 * (1.f / 256.f) - mn * mn;
        sstat[comp][t][0] = mn;
        sstat[comp][t][1] = rsqrtf(var + 1e-5f);
    }
    __syncthreads();
    const int comp = w >> 2;
#pragma unroll
    for (int j = 0; j < 4; ++j) {
        const int tl = j * 16 + brow;
        const float mn = sstat[comp][tl][0], rs = sstat[comp][tl][1];
        const int t = t0g + tl;
#pragma unroll
        for (int i = 0; i < 4; ++i) {
            const int m = w * 64 + i * 16 + q4;
            float* zp = &z[((size_t)b * 512 + m) * 2048 + t];
            const float gg[4] = {g4[i].x, g4[i].y, g4[i].z, g4[i].w};
            const float ee[4] = {e4[i].x, e4[i].y, e4[i].z, e4[i].w};
#pragma unroll
            for (int r = 0; r < 4; ++r)
                zp[(size_t)r * 2048] = (acc[i][j][r] - mn) * rs * gg[r] + ee[r];
        }
    }
}

// ---------- fused decoder: transpose+convert z in-stage, GEMM, paired out ----------
// R7 (verified): A rows interleaved (m' -> g=m'>>1, comp=m'&1) -> float2
// {re,im} full-line stores.
__global__ __launch_bounds__(512, 2) void mgemmdec_k(
    const unsigned short* __restrict__ A, const float* __restrict__ bias,
    const float* __restrict__ z, float* __restrict__ out)
{
    __shared__ unsigned short Bs[64][512];   // 64KB, swizzled
    const int tid = threadIdx.x;
    const int w = tid >> 6, lane = tid & 63;
    const int m0b = blockIdx.x * 384;
    const int t0g = blockIdx.y * 64, b = blockIdx.z;
    unsigned char* BsB = (unsigned char*)&Bs[0][0];

    // ---- stage B from z fp32 planes: f2bf + transpose-on-write ----
    {
        const float* zsrc = z + (size_t)b * 512 * 2048 + t0g;
        const int tseg = lane & 7, rloc = lane >> 3;
#pragma unroll
        for (int p = 0; p < 8; ++p) {
            const int krow = w * 8 + rloc + p * 64;
            const float* rowp = zsrc + (size_t)krow * 2048 + tseg * 8;
            const float4 va = *(const float4*)rowp;
            const float4 vb = *(const float4*)(rowp + 4);
            const float vals[8] = {va.x, va.y, va.z, va.w, vb.x, vb.y, vb.z, vb.w};
#pragma unroll
            for (int j = 0; j < 8; ++j) {
                const int t = tseg * 8 + j;
                const int mask = (((t & 7) ^ ((t >> 3) & 7)) << 4);
                *(unsigned short*)(BsB + t * 1024 + ((krow * 2) ^ mask)) = f2bf(vals[j]);
            }
        }
    }
    __syncthreads();

    // ---- K-loop: A direct from global, B from LDS ----
    float4v acc[3][4];
#pragma unroll
    for (int i = 0; i < 3; ++i)
#pragma unroll
        for (int j = 0; j < 4; ++j) acc[i][j] = (float4v){0.f, 0.f, 0.f, 0.f};

    const int brow = lane & 15;
    const int kq8 = (lane >> 4) * 8;
    const unsigned short* Ab = A + ((size_t)(m0b + w * 48 + brow)) * 512 + kq8;
    int baseB[4], maskB[4];
#pragma unroll
    for (int j = 0; j < 4; ++j) {
        const int t = j * 16 + brow;
        baseB[j] = t * 1024;
        maskB[j] = (((t & 7) ^ ((t >> 3) & 7)) << 4);
    }

#define LOADF(af_, bf_, k0_) do {                                              \
    _Pragma("unroll")                                                          \
    for (int i = 0; i < 3; ++i)                                                \
        af_[i] = *(const short8*)(Ab + (size_t)i * 16 * 512 + (k0_));          \
    _Pragma("unroll")                                                          \
    for (int j = 0; j < 4; ++j)                                                \
        bf_[j] = *(const short8*)(BsB + baseB[j] + ((((k0_) + kq8) * 2) ^ maskB[j])); \
} while (0)
#define MFMAS(af_, bf_) do {                                                   \
    _Pragma("unroll")                                                          \
    for (int i = 0; i < 3; ++i)                                                \
        _Pragma("unroll")                                                      \
        for (int j = 0; j < 4; ++j)                                            \
            acc[i][j] = __builtin_amdgcn_mfma_f32_16x16x32_bf16(af_[i], bf_[j], acc[i][j], 0, 0, 0); \
} while (0)

    {
        short8 afA[3], bfA[4], afB[3], bfB[4];
        LOADF(afA, bfA, 0);
#pragma unroll 1
        for (int kk = 0; kk < 16; kk += 2) {
            LOADF(afB, bfB, kk * 32 + 32);
            MFMAS(afA, bfA);
            if (kk + 2 < 16) LOADF(afA, bfA, kk * 32 + 64);
            MFMAS(afB, bfB);
        }
    }
#undef LOADF
#undef MFMAS

    // ---- epilogue: bias + paired float2 stores (g<514 guard) ----
    const int q4 = (lane >> 4) * 4;
#pragma unroll
    for (int i = 0; i < 3; ++i) {
        const int mb = m0b + w * 48 + i * 16 + q4;   // even
#pragma unroll
        for (int pr = 0; pr < 2; ++pr) {
            const int m2 = mb + pr * 2;              // even row of the pair
            const int g = m2 >> 1;
            if (g >= 514) continue;
            const float br = bias[m2], bi2 = bias[m2 + 1];
            float* op = out + (((size_t)b * 514 + g) * 2048 + t0g) * 2;
#pragma unroll
            for (int j = 0; j < 4; ++j) {
                const int tl = j * 16 + brow;
                const float2 v = make_float2(acc[i][j][pr * 2 + 0] + br,
                                             acc[i][j][pr * 2 + 1] + bi2);
                *(float2*)(op + (size_t)tl * 2) = v;
            }
        }
    }
}

// ---------- S4D diagonal SSM scan + D-skip + gelu -> bf16 planes ----------
// R3 design + R6 tweak (exclusive shift via store-to-lane+1 slot).
__global__ __launch_bounds__(256, 4) void s4scan_k(
    const float* __restrict__ z, unsigned short* __restrict__ y,
    const float* __restrict__ log_dt, const float* __restrict__ log_A_real,
    const float* __restrict__ A_imag, const float* __restrict__ C_r,
    const float* __restrict__ C_i, const float* __restrict__ Dsk, int l)
{
    const int h = blockIdx.x, b = blockIdx.y;
    const int tid = threadIdx.x;
    const int lane = tid & 63, wv = tid >> 6;
    __shared__ float2 wsh[32], csh[32];
    __shared__ float dsh;
    __shared__ float2 us[64][33];
    __shared__ __align__(16) unsigned char uni[64 * 33 * 8];
    float2 (*vsh2)[33] = (float2(*)[33])uni;
    float2 (*ys)[33]   = (float2(*)[33])uni;

    if (tid < 32) {
        const size_t pidx = ((size_t)l * 256 + h) * 32 + tid;
        const float dt = __expf(log_dt[l * 256 + h]);
        const float Ar = -__expf(log_A_real[pidx]);
        const float Ai = A_imag[pidx];
        const float er = __expf(Ar * dt);
        float sv, cv;
        __sincosf(Ai * dt, &sv, &cv);
        const float wr = er * cv, wi = er * sv;
        const float den = 1.f / (Ar * Ar + Ai * Ai);
        const float nr = wr - 1.f, ni = wi;
        const float qr = (nr * Ar + ni * Ai) * den;
        const float qi = (ni * Ar - nr * Ai) * den;
        const float cr = C_r[pidx], ci = C_i[pidx];
        wsh[tid] = make_float2(wr, wi);
        csh[tid] = make_float2(cr * qr - ci * qi, cr * qi + ci * qr);
    }
    if (tid == 32) dsh = Dsk[l * 256 + h];

    const int c0q = tid >> 2, t0q = (tid & 3) * 8;
    {
        const float* zrp = z + ((size_t)b * 512 + h) * 2048 + tid * 8;
        const float* zip = zrp + 256 * 2048;
        const float4 r0 = *(const float4*)zrp, r1 = *(const float4*)(zrp + 4);
        const float4 i0 = *(const float4*)zip, i1 = *(const float4*)(zip + 4);
        float2* up = &us[c0q][t0q];
        up[0] = make_float2(r0.x, i0.x); up[1] = make_float2(r0.y, i0.y);
        up[2] = make_float2(r0.z, i0.z); up[3] = make_float2(r0.w, i0.w);
        up[4] = make_float2(r1.x, i1.x); up[5] = make_float2(r1.y, i1.y);
        up[6] = make_float2(r1.z, i1.z); up[7] = make_float2(r1.w, i1.w);
    }
    __syncthreads();

    // ---- sweep 1: chunk-local finals + butterfly -> exclusive states ----
    {
        float2 w8[8], x8[8];
#pragma unroll
        for (int j = 0; j < 8; ++j) {
            w8[j] = wsh[wv * 8 + j];
            x8[j] = make_float2(0.f, 0.f);
        }
#pragma unroll 8
        for (int tt = 0; tt < 32; ++tt) {
            const float2 u = us[lane][tt];
#pragma unroll
            for (int j = 0; j < 8; ++j) {
                const float nxr = __builtin_fmaf(w8[j].x, x8[j].x, __builtin_fmaf(-w8[j].y, x8[j].y, u.x));
                const float nxi = __builtin_fmaf(w8[j].x, x8[j].y, __builtin_fmaf(w8[j].y, x8[j].x, u.y));
                x8[j].x = nxr; x8[j].y = nxi;
            }
        }
        const int dstc = (lane + 1) & 63;
#pragma unroll
        for (int j = 0; j < 8; ++j) {
            float fr = w8[j].x, fi = w8[j].y;
#pragma unroll
            for (int s = 0; s < 5; ++s) { const float a2 = fr * fr - fi * fi, b2 = 2.f * fr * fi; fr = a2; fi = b2; }
            float qrv = x8[j].x, qiv = x8[j].y, pr = fr, pi = fi;
#pragma unroll
            for (int s = 0; s < 6; ++s) {
                const int d = 1 << s;
                const float sr = __shfl_up(qrv, (unsigned)d);
                const float si = __shfl_up(qiv, (unsigned)d);
                if (lane >= d) {
                    qrv += pr * sr - pi * si;
                    qiv += pr * si + pi * sr;
                }
                const float a2 = pr * pr - pi * pi, b2 = 2.f * pr * pi;
                pr = a2; pi = b2;
            }
            vsh2[dstc][wv * 8 + j] = (lane == 63) ? make_float2(0.f, 0.f)
                                                  : make_float2(qrv, qiv);
        }
    }
    __syncthreads();

    // ---- sweep 2: single 8-mode pass, DPP reduce, ys written once ----
    {
        const int q = tid & 3;
        float2 w8[8], c8[8], s8[8];
#pragma unroll
        for (int j = 0; j < 8; ++j) {
            const int n = q * 8 + j;
            w8[j] = wsh[n];
            c8[j] = csh[n];
            s8[j] = vsh2[c0q][n];
        }
        __syncthreads();  // vsh2 fully in regs; ys may now overwrite it
#pragma unroll 4
        for (int tt = 0; tt < 32; ++tt) {
            const float2 u = us[c0q][tt];
            float pyr = 0.f, pyi = 0.f;
#pragma unroll
            for (int j = 0; j < 8; ++j) {
                const float nsr = __builtin_fmaf(w8[j].x, s8[j].x, __builtin_fmaf(-w8[j].y, s8[j].y, u.x));
                const float nsi = __builtin_fmaf(w8[j].x, s8[j].y, __builtin_fmaf(w8[j].y, s8[j].x, u.y));
                s8[j].x = nsr; s8[j].y = nsi;
                pyr = __builtin_fmaf(c8[j].x, nsr, __builtin_fmaf(-c8[j].y, nsi, pyr));
                pyi = __builtin_fmaf(c8[j].x, nsi, __builtin_fmaf(c8[j].y, nsr, pyi));
            }
            pyr = dppadd<DPP_XOR1>(pyr); pyr = dppadd<DPP_XOR2>(pyr);
            pyi = dppadd<DPP_XOR1>(pyi); pyi = dppadd<DPP_XOR2>(pyi);
            if (q == 0) ys[c0q][tt] = make_float2(pyr, pyi);
        }
    }
    __syncthreads();

    // ---- final: D-skip + gelu + bf16 pack + coalesced stores ----
    {
        const float dv = dsh;
        unsigned short* yrp = y + ((size_t)b * 512 + h) * 2048 + tid * 8;
        unsigned short* yip = yrp + 256 * 2048;
        short8 vr8, vi8;
#pragma unroll
        for (int j = 0; j < 8; ++j) {
            const float2 yv = ys[c0q][t0q + j];
            const float2 uv = us[c0q][t0q + j];
            ((unsigned short*)&vr8)[j] = f2bf(gelu_tanh(__builtin_fmaf(dv, uv.x, yv.x)));
            ((unsigned short*)&vi8)[j] = f2bf(gelu_tanh(__builtin_fmaf(dv, uv.y, yv.y)));
        }
        *(short8*)yrp = vr8;
        *(short8*)yip = vi8;
    }
}

extern "C" void kernel_launch(void* const* d_in, const int* in_sizes, int n_in,
                              void* d_out, int out_size, void* d_ws, size_t ws_size,
                              hipStream_t stream)
{
    const float* x        = (const float*)d_in[0];
    const float* enc_Wr   = (const float*)d_in[1];
    const float* enc_Wi   = (const float*)d_in[2];
    const float* enc_br   = (const float*)d_in[3];
    const float* enc_bi   = (const float*)d_in[4];
    const float* log_dt   = (const float*)d_in[5];
    const float* log_A_r  = (const float*)d_in[6];
    const float* A_imag   = (const float*)d_in[7];
    const float* C_r      = (const float*)d_in[8];
    const float* C_i      = (const float*)d_in[9];
    const float* Dp       = (const float*)d_in[10];
    const float* out_Wr   = (const float*)d_in[11];
    const float* out_Wi   = (const float*)d_in[12];
    const float* out_br   = (const float*)d_in[13];
    const float* out_bi   = (const float*)d_in[14];
    const float* ln_gr    = (const float*)d_in[15];
    const float* ln_gi    = (const float*)d_in[16];
    const float* ln_br    = (const float*)d_in[17];
    const float* ln_bi    = (const float*)d_in[18];
    const float* dec_Wr   = (const float*)d_in[19];
    const float* dec_Wi   = (const float*)d_in[20];
    const float* dec_br   = (const float*)d_in[21];
    const float* dec_bi   = (const float*)d_in[22];

    // ---- workspace layout (bytes) ----
    uint8_t* W = (uint8_t*)d_ws;
    float* z             = (float*)W;                       // 33,554,432
    unsigned short* A_enc= (unsigned short*)(W + 50331648); // 512x1056x2  = 1,081,344
    unsigned short* A_lay= (unsigned short*)(W + 51412992); // 4x512x512x2 = 2,097,152
    unsigned short* A_dec= (unsigned short*)(W + 53510144); // 1152x512x2  = 1,179,648
    float* b_enc         = (float*)(W + 54689792);          // 512 f
    float* b_lay         = (float*)(W + 54691840);          // 2048 f
    float* b_dec         = (float*)(W + 54700032);          // 1028 f

    // ---- d_out doubles as scratch ----
    unsigned short* y   = (unsigned short*)((uint8_t*)d_out + 33554432);   // 16,777,216
    unsigned short* xp  = (unsigned short*)d_out;  // 34,603,008; dead after encoder GEMM

    // ---- build all weights/biases in one launch ----
    buildall_k<<<8527, 256, 0, stream>>>(enc_Wr, enc_Wi, out_Wr, out_Wi,
                                         dec_Wr, dec_Wi, enc_br, enc_bi,
                                         out_br, out_bi, dec_br, dec_bi,
                                         A_enc, A_lay, A_dec,
                                         b_enc, b_lay, b_dec);

    // ---- encoder: pack x -> xp, GEMM -> z ----
    packx_k<<<dim3(32, 9, 8), 256, 0, stream>>>(x, xp);
    mgemm_k<<<dim3(4, 16, 8), 256, 0, stream>>>(A_enc, b_enc, xp, z, 512, 1056);

    // ---- layers: scan -> fused transpose+GEMM+residual+LN ----
    for (int l = 0; l < 4; ++l) {
        s4scan_k<<<dim3(256, 8), 256, 0, stream>>>(z, y, log_dt, log_A_r, A_imag, C_r, C_i, Dp, l);
        mgemmln_k<<<dim3(32, 8), 512, 0, stream>>>(A_lay + (size_t)l * 262144,
                                                   b_lay + l * 512, y, z,
                                                   ln_gr, ln_gi, ln_br, ln_bi, l);
    }

    // ---- decoder: fused transpose+convert+GEMM -> d_out paired stores ----
    mgemmdec_k<<<dim3(3, 32, 8), 512, 0, stream>>>(A_dec, b_dec, z, (float*)d_out);
}

// Round 10
// 558.582 us; speedup vs baseline: 1.1516x; 1.0534x over previous
//
#include <hip/hip_runtime.h>
#include <cstddef>
#include <cstdint>

// B=8, C=2, Hf=257, T=2048, D_IN=514, DM=256, NL=4, N=32
// Activations: fp32 planes (b, 2*DM=512, T). GEMMs run bf16 MFMA.
// R10: s4scan complex arithmetic moved to v_pk_fma_f32 (VOP3P packed 2xfp32
// with op_sel/neg half-select): one complex mul-add = 2 packed FMA instead
// of 4 scalar -> s4scan VALU stream ~halves (47us issue -> ~25us).
// Everything else identical to R9 (verified best).

typedef __attribute__((ext_vector_type(8))) short short8;
typedef __attribute__((ext_vector_type(4))) float float4v;

__device__ __forceinline__ unsigned short f2bf(float f) {
    union { float f; unsigned u; } v; v.f = f;
    const unsigned r = v.u + 0x7fffu + ((v.u >> 16) & 1u);  // RNE
    return (unsigned short)(r >> 16);
}

__device__ __forceinline__ float gelu_tanh(float x) {
    const float x3 = x * x * x;
    const float v  = 0.7978845608028654f * (x + 0.044715f * x3);
    const float e  = __expf(2.f * v);
    const float th = 1.f - 2.f / (e + 1.f);
    return 0.5f * x * (1.f + th);
}

// packed complex mul-add: returns w (*) p + u  (complex product), using
// 2x v_pk_fma_f32 (VOP3P) instead of 4 scalar FMA.
//   t.lo = -w.hi*p.hi + u.lo ; t.hi = w.hi*p.lo + u.hi
//   r.lo =  w.lo*p.lo + t.lo ; r.hi = w.lo*p.hi + t.hi
__device__ __forceinline__ float2 cfma(const float2 w, const float2 p,
                                       const float2 u) {
    float2 t, r;
    asm("v_pk_fma_f32 %0, %1, %2, %3 op_sel:[1,1,0] op_sel_hi:[1,0,1] neg_lo:[1,0,0] neg_hi:[0,0,0]"
        : "=v"(t) : "v"(w), "v"(p), "v"(u));
    asm("v_pk_fma_f32 %0, %1, %2, %3 op_sel:[0,0,0] op_sel_hi:[0,1,1]"
        : "=v"(r) : "v"(w), "v"(p), "v"(t));
    return r;
}

// quad-perm DPP add: returns x + x[lane ^ k] for k in {1,2} (pure VALU).
template<int CTL>
__device__ __forceinline__ float dppadd(float x) {
    union { float f; int i; } a, r;
    a.f = x;
    r.i = __builtin_amdgcn_update_dpp(a.i, a.i, CTL, 0xF, 0xF, true);
    return x + r.f;
}
#define DPP_XOR1 0xB1  // quad_perm [1,0,3,2]
#define DPP_XOR2 0x4E  // quad_perm [2,3,0,1]

#define ASYNC_COPY16(gp, lp) __builtin_amdgcn_global_load_lds( \
    (const __attribute__((address_space(1))) unsigned int*)(gp), \
    (__attribute__((address_space(3))) unsigned int*)(lp), 16, 0, 0)

// ---------- ONE builder launch for all weights/biases ----------
__global__ __launch_bounds__(256) void buildall_k(
    const float* __restrict__ enc_Wr, const float* __restrict__ enc_Wi,
    const float* __restrict__ out_Wr, const float* __restrict__ out_Wi,
    const float* __restrict__ dec_Wr, const float* __restrict__ dec_Wi,
    const float* __restrict__ enc_br, const float* __restrict__ enc_bi,
    const float* __restrict__ out_br, const float* __restrict__ out_bi,
    const float* __restrict__ dec_br, const float* __restrict__ dec_bi,
    unsigned short* __restrict__ A_enc, unsigned short* __restrict__ A_lay,
    unsigned short* __restrict__ A_dec,
    float* __restrict__ b_enc, float* __restrict__ b_lay,
    float* __restrict__ b_dec)
{
    int blk = blockIdx.x;
    const int tid = threadIdx.x;
    if (blk < 2112) {
        const int i = blk * 256 + tid;
        const int m = i / 1056, k = i - m * 1056;
        const int ri = m >= 256, g = m & 255;
        const int blk2 = k >= 528;
        const int hh = k - blk2 * 528;
        float val = 0.f;
        if (hh < 514) {
            const float wr = enc_Wr[(size_t)g * 514 + hh];
            const float wi = enc_Wi[(size_t)g * 514 + hh];
            val = ri ? (blk2 ? wr : wi) : (blk2 ? -wi : wr);
        }
        A_enc[i] = f2bf(val);
        return;
    }
    blk -= 2112;
    if (blk < 4096) {
        const int l = blk >> 10;
        const int i = ((blk & 1023) << 8) + tid;
        const float* Wr = out_Wr + (size_t)l * 65536;
        const float* Wi = out_Wi + (size_t)l * 65536;
        const int m = i >> 9, k = i & 511;
        const int ri = m >= 256, g = m & 255;
        const int blk2 = k >> 8, hh = k & 255;
        const float wr = Wr[(size_t)g * 256 + hh];
        const float wi = Wi[(size_t)g * 256 + hh];
        A_lay[(size_t)l * 262144 + i] =
            f2bf(ri ? (blk2 ? wr : wi) : (blk2 ? -wi : wr));
        return;
    }
    blk -= 4096;
    if (blk < 2304) {
        // decoder W, INTERLEAVED rows: m' -> (g = m'>>1, comp = m'&1).
        const int i = blk * 256 + tid;
        const int m = i >> 9, k = i & 511;
        const int g = m >> 1, comp = m & 1;
        float val = 0.f;
        if (g < 514) {
            const int blk2 = k >> 8, hh = k & 255;
            const float wr = dec_Wr[(size_t)g * 256 + hh];
            const float wi = dec_Wi[(size_t)g * 256 + hh];
            val = comp ? (blk2 ? wr : wi) : (blk2 ? -wi : wr);
        }
        A_dec[i] = f2bf(val);
        return;
    }
    blk -= 2304;
    if (blk < 2) {
        const int i = blk * 256 + tid;
        b_enc[i] = (i < 256) ? enc_br[i] : enc_bi[i - 256];
        return;
    }
    blk -= 2;
    if (blk < 8) {
        const int l = blk >> 1;
        const int i = ((blk & 1) << 8) + tid;
        b_lay[l * 512 + i] = (i < 256) ? out_br[l * 256 + i]
                                       : out_bi[l * 256 + i - 256];
        return;
    }
    blk -= 8;
    {
        const int i = blk * 256 + tid;
        if (i < 1028) b_dec[i] = (i & 1) ? dec_bi[i >> 1] : dec_br[i >> 1];
    }
}

// ---------- encoder input pack: x (b,514,T,2) fp32 -> xp (b,T,1056) bf16 ----------
__global__ __launch_bounds__(256) void packx_k(const float* __restrict__ x,
                                               unsigned short* __restrict__ xp)
{
    const int t0 = blockIdx.x * 64, d0 = blockIdx.y * 64, b = blockIdx.z;
    __shared__ unsigned short tr_[64][72];
    __shared__ unsigned short ti_[64][72];
    const int tid = threadIdx.x;
    const int tp = tid & 31, dl0 = tid >> 5;
#pragma unroll
    for (int p = 0; p < 8; ++p) {
        const int d = dl0 + p * 8;
        const int gd = d0 + d;
        float4 v = make_float4(0.f, 0.f, 0.f, 0.f);
        if (gd < 514) v = *(const float4*)(x + (((size_t)b * 514 + gd) * 2048 + t0 + tp * 2) * 2);
        tr_[tp * 2 + 0][d] = f2bf(v.x); ti_[tp * 2 + 0][d] = f2bf(v.y);
        tr_[tp * 2 + 1][d] = f2bf(v.z); ti_[tp * 2 + 1][d] = f2bf(v.w);
    }
    __syncthreads();
    const int dc = tid & 7;
    const int kloc = d0 + dc * 8;
    if (kloc < 528) {
#pragma unroll
        for (int p = 0; p < 2; ++p) {
            const int t = (tid >> 3) + p * 32;
            const size_t rowb = ((size_t)b * 2048 + t0 + t) * 1056;
            *(short8*)&xp[rowb + kloc]       = *(const short8*)&tr_[t][dc * 8];
            *(short8*)&xp[rowb + 528 + kloc] = *(const short8*)&ti_[t][dc * 8];
        }
    }
}

// ---------- bf16 MFMA GEMM (encoder): out(b,M,T) = A * Bm^T + bias ----------
__global__ __launch_bounds__(256, 2) void mgemm_k(
    const unsigned short* __restrict__ A, const float* __restrict__ bias,
    const unsigned short* __restrict__ Bm, float* __restrict__ out,
    int M, int Kp)
{
    __shared__ unsigned short As[4096];  // [m 0..127][k 0..31]
    __shared__ unsigned short Bs[4096];  // [t 0..127][k 0..31]
    const int tid = threadIdx.x;
    const int w = tid >> 6, lane = tid & 63;
    const int m0 = blockIdx.x * 128, t0 = blockIdx.y * 128, b = blockIdx.z;
    const int wm = w & 1, wn = w >> 1;

    const unsigned short* Ab = A + (size_t)m0 * Kp;
    const unsigned short* Bb = Bm + ((size_t)b * 2048 + t0) * Kp;

    const int c0 = w * 64 + lane;
    const int r0 = c0 >> 2, q0 = (c0 & 3) * 8;
    const int c1 = c0 + 256;
    const int r1 = c1 >> 2, q1 = (c1 & 3) * 8;
    unsigned short* As0 = &As[(size_t)(w * 64) * 8];
    unsigned short* As1 = &As[(size_t)(w * 64 + 256) * 8];
    unsigned short* Bs0 = &Bs[(size_t)(w * 64) * 8];
    unsigned short* Bs1 = &Bs[(size_t)(w * 64 + 256) * 8];

    float4v acc[4][4];
#pragma unroll
    for (int i = 0; i < 4; ++i)
#pragma unroll
        for (int j = 0; j < 4; ++j) acc[i][j] = (float4v){0.f, 0.f, 0.f, 0.f};

    const int arow = wm * 64 + (lane & 15);
    const int brow = wn * 64 + (lane & 15);
    const int kq = (lane >> 4) * 8;

    for (int k0 = 0; k0 < Kp; k0 += 32) {
        ASYNC_COPY16(Ab + (size_t)r0 * Kp + k0 + q0, As0);
        ASYNC_COPY16(Ab + (size_t)r1 * Kp + k0 + q1, As1);
        ASYNC_COPY16(Bb + (size_t)r0 * Kp + k0 + q0, Bs0);
        ASYNC_COPY16(Bb + (size_t)r1 * Kp + k0 + q1, Bs1);
        __syncthreads();
        short8 af[4], bf[4];
#pragma unroll
        for (int i = 0; i < 4; ++i) af[i] = *(const short8*)&As[(arow + i * 16) * 32 + kq];
#pragma unroll
        for (int j = 0; j < 4; ++j) bf[j] = *(const short8*)&Bs[(brow + j * 16) * 32 + kq];
#pragma unroll
        for (int i = 0; i < 4; ++i)
#pragma unroll
            for (int j = 0; j < 4; ++j)
                acc[i][j] = __builtin_amdgcn_mfma_f32_16x16x32_bf16(af[i], bf[j], acc[i][j], 0, 0, 0);
        __syncthreads();
    }

    const int col = lane & 15;
    const int rq = (lane >> 4) * 4;
#pragma unroll
    for (int i = 0; i < 4; ++i) {
        const int mloc = wm * 64 + i * 16 + rq;
#pragma unroll
        for (int r = 0; r < 4; ++r) {
            const int m = m0 + mloc + r;
            const float bs = bias[m];
#pragma unroll
            for (int j = 0; j < 4; ++j) {
                const int t = t0 + wn * 64 + j * 16 + col;
                out[((size_t)b * 512 + m) * 2048 + t] = acc[i][j][r] + bs;
            }
        }
    }
}

// ---------- fused layer GEMM + residual + channel LayerNorm ----------
// R7 verified optimum: 64-t tile, B staged directly from t-major y planes
// (transpose on the LDS write), XOR swizzle mask(t) = ((t&7)^((t>>3)&7))<<4.
__global__ __launch_bounds__(512, 2) void mgemmln_k(
    const unsigned short* __restrict__ A, const float* __restrict__ bias,
    const unsigned short* __restrict__ Bm, float* __restrict__ z,
    const float* __restrict__ gamr, const float* __restrict__ gami,
    const float* __restrict__ betr, const float* __restrict__ beti, int l)
{
    __shared__ unsigned short Bs[64][512];   // 64KB, swizzled
    __shared__ float biasS[512], gamS[512], betS[512];
    __shared__ float sred[8][64][2];
    __shared__ float sstat[2][64][2];
    const int tid = threadIdx.x;
    const int w = tid >> 6, lane = tid & 63;
    const int t0g = blockIdx.x * 64, b = blockIdx.y;
    unsigned char* BsB = (unsigned char*)&Bs[0][0];

    // ---- stage B from y planes, transpose-on-write ----
    {
        const unsigned short* ysrc = Bm + (size_t)b * 512 * 2048 + t0g;
        const int tseg = lane & 7;       // 8-t segment (t = tseg*8 + j)
        const int rloc = lane >> 3;      // row within the wave's octet
#pragma unroll
        for (int p = 0; p < 8; ++p) {
            const int krow = w * 8 + rloc + p * 64;
            const short8 v = *(const short8*)(ysrc + (size_t)krow * 2048 + tseg * 8);
#pragma unroll
            for (int j = 0; j < 8; ++j) {
                const int t = tseg * 8 + j;
                const int mask = (((t & 7) ^ ((t >> 3) & 7)) << 4);
                *(unsigned short*)(BsB + t * 1024 + ((krow * 2) ^ mask)) =
                    ((const unsigned short*)&v)[j];
            }
        }
        const int m = tid, g = m & 255, comp = m >> 8;
        biasS[m] = bias[m];
        gamS[m] = (comp ? gami : gamr)[l * 256 + g];
        betS[m] = (comp ? beti : betr)[l * 256 + g];
    }
    __syncthreads();

    // ---- K-loop: A direct from global (L2-resident), B from LDS ----
    float4v acc[4][4];
#pragma unroll
    for (int i = 0; i < 4; ++i)
#pragma unroll
        for (int j = 0; j < 4; ++j) acc[i][j] = (float4v){0.f, 0.f, 0.f, 0.f};

    const int brow = lane & 15;
    const int kq8 = (lane >> 4) * 8;
    const unsigned short* Ab = A + ((size_t)(w * 64 + brow)) * 512 + kq8;
    int baseB[4], maskB[4];
#pragma unroll
    for (int j = 0; j < 4; ++j) {
        const int t = j * 16 + brow;
        baseB[j] = t * 1024;
        maskB[j] = (((t & 7) ^ ((t >> 3) & 7)) << 4);
    }

#define LOADF(af_, bf_, k0_) do {                                              \
    _Pragma("unroll")                                                          \
    for (int i = 0; i < 4; ++i)                                                \
        af_[i] = *(const short8*)(Ab + (size_t)i * 16 * 512 + (k0_));          \
    _Pragma("unroll")                                                          \
    for (int j = 0; j < 4; ++j)                                                \
        bf_[j] = *(const short8*)(BsB + baseB[j] + ((((k0_) + kq8) * 2) ^ maskB[j])); \
} while (0)
#define MFMAS(af_, bf_) do {                                                   \
    _Pragma("unroll")                                                          \
    for (int i = 0; i < 4; ++i)                                                \
        _Pragma("unroll")                                                      \
        for (int j = 0; j < 4; ++j)                                            \
            acc[i][j] = __builtin_amdgcn_mfma_f32_16x16x32_bf16(af_[i], bf_[j], acc[i][j], 0, 0, 0); \
} while (0)

    {
        short8 afA[4], bfA[4], afB[4], bfB[4];
        LOADF(afA, bfA, 0);
#pragma unroll 1
        for (int kk = 0; kk < 16; kk += 2) {
            LOADF(afB, bfB, kk * 32 + 32);
            MFMAS(afA, bfA);
            if (kk + 2 < 16) LOADF(afA, bfA, kk * 32 + 64);
            MFMAS(afB, bfB);
        }
    }
#undef LOADF
#undef MFMAS

    // ---- epilogue: v = acc + bias + z_old, LN stats, normalize, write z ----
    const int q4 = (lane >> 4) * 4;
    float4 b4[4], g4[4], e4[4];
#pragma unroll
    for (int i = 0; i < 4; ++i) {
        const int m0 = w * 64 + i * 16 + q4;
        b4[i] = *(const float4*)&biasS[m0];
        g4[i] = *(const float4*)&gamS[m0];
        e4[i] = *(const float4*)&betS[m0];
    }

    float s1[4], s2[4];
#pragma unroll
    for (int j = 0; j < 4; ++j) { s1[j] = 0.f; s2[j] = 0.f; }
#pragma unroll
    for (int j = 0; j < 4; ++j) {
        const int t = t0g + j * 16 + brow;
#pragma unroll
        for (int i = 0; i < 4; ++i) {
            const int m = w * 64 + i * 16 + q4;
            const float* zp = &z[((size_t)b * 512 + m) * 2048 + t];
            const float bb[4] = {b4[i].x, b4[i].y, b4[i].z, b4[i].w};
#pragma unroll
            for (int r = 0; r < 4; ++r) {
                const float v = acc[i][j][r] + bb[r] + zp[(size_t)r * 2048];
                acc[i][j][r] = v;
                s1[j] += v; s2[j] += v * v;
            }
        }
    }
#pragma unroll
    for (int j = 0; j < 4; ++j) {
        s1[j] += __shfl_xor(s1[j], 16); s2[j] += __shfl_xor(s2[j], 16);
        s1[j] += __shfl_xor(s1[j], 32); s2[j] += __shfl_xor(s2[j], 32);
    }
    if (lane < 16) {
#pragma unroll
        for (int j = 0; j < 4; ++j) {
            sred[w][j * 16 + lane][0] = s1[j];
            sred[w][j * 16 + lane][1] = s2[j];
        }
    }
    __syncthreads();
    if (tid < 128) {
        const int t = tid & 63, comp = tid >> 6;
        float S1 = 0.f, S2 = 0.f;
#pragma unroll
        for (int w2 = 0; w2 < 4; ++w2) {
            S1 += sred[comp * 4 + w2][t][0];
            S2 += sred[comp * 4 + w2][t][1];
        }
        const float mn = S1 * (1.f / 256.f);
        const float var = S2 * (1.f / 256.f) - mn * mn;
        sstat[comp][t][0] = mn;
        sstat[comp][t][1] = rsqrtf(var + 1e-5f);
    }
    __syncthreads();
    const int comp = w >> 2;
#pragma unroll
    for (int j = 0; j < 4; ++j) {
        const int tl = j * 16 + brow;
        const float mn = sstat[comp][tl][0], rs = sstat[comp][tl][1];
        const int t = t0g + tl;
#pragma unroll
        for (int i = 0; i < 4; ++i) {
            const int m = w * 64 + i * 16 + q4;
            float* zp = &z[((size_t)b * 512 + m) * 2048 + t];
            const float gg[4] = {g4[i].x, g4[i].y, g4[i].z, g4[i].w};
            const float ee[4] = {e4[i].x, e4[i].y, e4[i].z, e4[i].w};
#pragma unroll
            for (int r = 0; r < 4; ++r)
                zp[(size_t)r * 2048] = (acc[i][j][r] - mn) * rs * gg[r] + ee[r];
        }
    }
}

// ---------- fused decoder: transpose+convert z in-stage, GEMM, paired out ----------
// R7 (verified): A rows interleaved (m' -> g=m'>>1, comp=m'&1) -> float2
// {re,im} full-line stores.
__global__ __launch_bounds__(512, 2) void mgemmdec_k(
    const unsigned short* __restrict__ A, const float* __restrict__ bias,
    const float* __restrict__ z, float* __restrict__ out)
{
    __shared__ unsigned short Bs[64][512];   // 64KB, swizzled
    const int tid = threadIdx.x;
    const int w = tid >> 6, lane = tid & 63;
    const int m0b = blockIdx.x * 384;
    const int t0g = blockIdx.y * 64, b = blockIdx.z;
    unsigned char* BsB = (unsigned char*)&Bs[0][0];

    // ---- stage B from z fp32 planes: f2bf + transpose-on-write ----
    {
        const float* zsrc = z + (size_t)b * 512 * 2048 + t0g;
        const int tseg = lane & 7, rloc = lane >> 3;
#pragma unroll
        for (int p = 0; p < 8; ++p) {
            const int krow = w * 8 + rloc + p * 64;
            const float* rowp = zsrc + (size_t)krow * 2048 + tseg * 8;
            const float4 va = *(const float4*)rowp;
            const float4 vb = *(const float4*)(rowp + 4);
            const float vals[8] = {va.x, va.y, va.z, va.w, vb.x, vb.y, vb.z, vb.w};
#pragma unroll
            for (int j = 0; j < 8; ++j) {
                const int t = tseg * 8 + j;
                const int mask = (((t & 7) ^ ((t >> 3) & 7)) << 4);
                *(unsigned short*)(BsB + t * 1024 + ((krow * 2) ^ mask)) = f2bf(vals[j]);
            }
        }
    }
    __syncthreads();

    // ---- K-loop: A direct from global, B from LDS ----
    float4v acc[3][4];
#pragma unroll
    for (int i = 0; i < 3; ++i)
#pragma unroll
        for (int j = 0; j < 4; ++j) acc[i][j] = (float4v){0.f, 0.f, 0.f, 0.f};

    const int brow = lane & 15;
    const int kq8 = (lane >> 4) * 8;
    const unsigned short* Ab = A + ((size_t)(m0b + w * 48 + brow)) * 512 + kq8;
    int baseB[4], maskB[4];
#pragma unroll
    for (int j = 0; j < 4; ++j) {
        const int t = j * 16 + brow;
        baseB[j] = t * 1024;
        maskB[j] = (((t & 7) ^ ((t >> 3) & 7)) << 4);
    }

#define LOADF(af_, bf_, k0_) do {                                              \
    _Pragma("unroll")                                                          \
    for (int i = 0; i < 3; ++i)                                                \
        af_[i] = *(const short8*)(Ab + (size_t)i * 16 * 512 + (k0_));          \
    _Pragma("unroll")                                                          \
    for (int j = 0; j < 4; ++j)                                                \
        bf_[j] = *(const short8*)(BsB + baseB[j] + ((((k0_) + kq8) * 2) ^ maskB[j])); \
} while (0)
#define MFMAS(af_, bf_) do {                                                   \
    _Pragma("unroll")                                                          \
    for (int i = 0; i < 3; ++i)                                                \
        _Pragma("unroll")                                                      \
        for (int j = 0; j < 4; ++j)                                            \
            acc[i][j] = __builtin_amdgcn_mfma_f32_16x16x32_bf16(af_[i], bf_[j], acc[i][j], 0, 0, 0); \
} while (0)

    {
        short8 afA[3], bfA[4], afB[3], bfB[4];
        LOADF(afA, bfA, 0);
#pragma unroll 1
        for (int kk = 0; kk < 16; kk += 2) {
            LOADF(afB, bfB, kk * 32 + 32);
            MFMAS(afA, bfA);
            if (kk + 2 < 16) LOADF(afA, bfA, kk * 32 + 64);
            MFMAS(afB, bfB);
        }
    }
#undef LOADF
#undef MFMAS

    // ---- epilogue: bias + paired float2 stores (g<514 guard) ----
    const int q4 = (lane >> 4) * 4;
#pragma unroll
    for (int i = 0; i < 3; ++i) {
        const int mb = m0b + w * 48 + i * 16 + q4;   // even
#pragma unroll
        for (int pr = 0; pr < 2; ++pr) {
            const int m2 = mb + pr * 2;              // even row of the pair
            const int g = m2 >> 1;
            if (g >= 514) continue;
            const float br = bias[m2], bi2 = bias[m2 + 1];
            float* op = out + (((size_t)b * 514 + g) * 2048 + t0g) * 2;
#pragma unroll
            for (int j = 0; j < 4; ++j) {
                const int tl = j * 16 + brow;
                const float2 v = make_float2(acc[i][j][pr * 2 + 0] + br,
                                             acc[i][j][pr * 2 + 1] + bi2);
                *(float2*)(op + (size_t)tl * 2) = v;
            }
        }
    }
}

// ---------- S4D diagonal SSM scan + D-skip + gelu -> bf16 planes ----------
// R3 structure + R6 exclusive-shift + R10 packed complex arithmetic
// (v_pk_fma_f32 via cfma): sweep1/sweep2/butterfly FMA streams halved.
__global__ __launch_bounds__(256, 4) void s4scan_k(
    const float* __restrict__ z, unsigned short* __restrict__ y,
    const float* __restrict__ log_dt, const float* __restrict__ log_A_real,
    const float* __restrict__ A_imag, const float* __restrict__ C_r,
    const float* __restrict__ C_i, const float* __restrict__ Dsk, int l)
{
    const int h = blockIdx.x, b = blockIdx.y;
    const int tid = threadIdx.x;
    const int lane = tid & 63, wv = tid >> 6;
    __shared__ float2 wsh[32], csh[32];
    __shared__ float dsh;
    __shared__ float2 us[64][33];
    __shared__ __align__(16) unsigned char uni[64 * 33 * 8];
    float2 (*vsh2)[33] = (float2(*)[33])uni;
    float2 (*ys)[33]   = (float2(*)[33])uni;

    if (tid < 32) {
        const size_t pidx = ((size_t)l * 256 + h) * 32 + tid;
        const float dt = __expf(log_dt[l * 256 + h]);
        const float Ar = -__expf(log_A_real[pidx]);
        const float Ai = A_imag[pidx];
        const float er = __expf(Ar * dt);
        float sv, cv;
        __sincosf(Ai * dt, &sv, &cv);
        const float wr = er * cv, wi = er * sv;
        const float den = 1.f / (Ar * Ar + Ai * Ai);
        const float nr = wr - 1.f, ni = wi;
        const float qr = (nr * Ar + ni * Ai) * den;
        const float qi = (ni * Ar - nr * Ai) * den;
        const float cr = C_r[pidx], ci = C_i[pidx];
        wsh[tid] = make_float2(wr, wi);
        csh[tid] = make_float2(cr * qr - ci * qi, cr * qi + ci * qr);
    }
    if (tid == 32) dsh = Dsk[l * 256 + h];

    const int c0q = tid >> 2, t0q = (tid & 3) * 8;
    {
        const float* zrp = z + ((size_t)b * 512 + h) * 2048 + tid * 8;
        const float* zip = zrp + 256 * 2048;
        const float4 r0 = *(const float4*)zrp, r1 = *(const float4*)(zrp + 4);
        const float4 i0 = *(const float4*)zip, i1 = *(const float4*)(zip + 4);
        float2* up = &us[c0q][t0q];
        up[0] = make_float2(r0.x, i0.x); up[1] = make_float2(r0.y, i0.y);
        up[2] = make_float2(r0.z, i0.z); up[3] = make_float2(r0.w, i0.w);
        up[4] = make_float2(r1.x, i1.x); up[5] = make_float2(r1.y, i1.y);
        up[6] = make_float2(r1.z, i1.z); up[7] = make_float2(r1.w, i1.w);
    }
    __syncthreads();

    const float2 zero2 = make_float2(0.f, 0.f);

    // ---- sweep 1: chunk-local finals + butterfly -> exclusive states ----
    {
        float2 w8[8], x8[8];
#pragma unroll
        for (int j = 0; j < 8; ++j) {
            w8[j] = wsh[wv * 8 + j];
            x8[j] = zero2;
        }
#pragma unroll 8
        for (int tt = 0; tt < 32; ++tt) {
            const float2 u = us[lane][tt];
#pragma unroll
            for (int j = 0; j < 8; ++j) x8[j] = cfma(w8[j], x8[j], u);
        }
        const int dstc = (lane + 1) & 63;
#pragma unroll
        for (int j = 0; j < 8; ++j) {
            // f = w^32 via 5 complex squarings (packed)
            float2 f = w8[j];
#pragma unroll
            for (int s = 0; s < 5; ++s) f = cfma(f, f, zero2);
            // inclusive wave prefix over chunk-final states, multiplier f
            float2 qv = x8[j], pq = f;
#pragma unroll
            for (int s = 0; s < 6; ++s) {
                const int d = 1 << s;
                float2 sh;
                sh.x = __shfl_up(qv.x, (unsigned)d);
                sh.y = __shfl_up(qv.y, (unsigned)d);
                const float2 qn = cfma(pq, sh, qv);
                if (lane >= d) qv = qn;
                pq = cfma(pq, pq, zero2);
            }
            vsh2[dstc][wv * 8 + j] = (lane == 63) ? zero2 : qv;
        }
    }
    __syncthreads();

    // ---- sweep 2: single 8-mode pass, DPP reduce, ys written once ----
    {
        const int q = tid & 3;
        float2 w8[8], c8[8], s8[8];
#pragma unroll
        for (int j = 0; j < 8; ++j) {
            const int n = q * 8 + j;
            w8[j] = wsh[n];
            c8[j] = csh[n];
            s8[j] = vsh2[c0q][n];
        }
        __syncthreads();  // vsh2 fully in regs; ys may now overwrite it
#pragma unroll 4
        for (int tt = 0; tt < 32; ++tt) {
            const float2 u = us[c0q][tt];
            float2 py = zero2;
#pragma unroll
            for (int j = 0; j < 8; ++j) {
                s8[j] = cfma(w8[j], s8[j], u);
                py = cfma(c8[j], s8[j], py);
            }
            py.x = dppadd<DPP_XOR1>(py.x); py.x = dppadd<DPP_XOR2>(py.x);
            py.y = dppadd<DPP_XOR1>(py.y); py.y = dppadd<DPP_XOR2>(py.y);
            if (q == 0) ys[c0q][tt] = py;
        }
    }
    __syncthreads();

    // ---- final: D-skip + gelu + bf16 pack + coalesced stores ----
    {
        const float dv = dsh;
        unsigned short* yrp = y + ((size_t)b * 512 + h) * 2048 + tid * 8;
        unsigned short* yip = yrp + 256 * 2048;
        short8 vr8, vi8;
#pragma unroll
        for (int j = 0; j < 8; ++j) {
            const float2 yv = ys[c0q][t0q + j];
            const float2 uv = us[c0q][t0q + j];
            ((unsigned short*)&vr8)[j] = f2bf(gelu_tanh(__builtin_fmaf(dv, uv.x, yv.x)));
            ((unsigned short*)&vi8)[j] = f2bf(gelu_tanh(__builtin_fmaf(dv, uv.y, yv.y)));
        }
        *(short8*)yrp = vr8;
        *(short8*)yip = vi8;
    }
}

extern "C" void kernel_launch(void* const* d_in, const int* in_sizes, int n_in,
                              void* d_out, int out_size, void* d_ws, size_t ws_size,
                              hipStream_t stream)
{
    const float* x        = (const float*)d_in[0];
    const float* enc_Wr   = (const float*)d_in[1];
    const float* enc_Wi   = (const float*)d_in[2];
    const float* enc_br   = (const float*)d_in[3];
    const float* enc_bi   = (const float*)d_in[4];
    const float* log_dt   = (const float*)d_in[5];
    const float* log_A_r  = (const float*)d_in[6];
    const float* A_imag   = (const float*)d_in[7];
    const float* C_r      = (const float*)d_in[8];
    const float* C_i      = (const float*)d_in[9];
    const float* Dp       = (const float*)d_in[10];
    const float* out_Wr   = (const float*)d_in[11];
    const float* out_Wi   = (const float*)d_in[12];
    const float* out_br   = (const float*)d_in[13];
    const float* out_bi   = (const float*)d_in[14];
    const float* ln_gr    = (const float*)d_in[15];
    const float* ln_gi    = (const float*)d_in[16];
    const float* ln_br    = (const float*)d_in[17];
    const float* ln_bi    = (const float*)d_in[18];
    const float* dec_Wr   = (const float*)d_in[19];
    const float* dec_Wi   = (const float*)d_in[20];
    const float* dec_br   = (const float*)d_in[21];
    const float* dec_bi   = (const float*)d_in[22];

    // ---- workspace layout (bytes) ----
    uint8_t* W = (uint8_t*)d_ws;
    float* z             = (float*)W;                       // 33,554,432
    unsigned short* A_enc= (unsigned short*)(W + 50331648); // 512x1056x2  = 1,081,344
    unsigned short* A_lay= (unsigned short*)(W + 51412992); // 4x512x512x2 = 2,097,152
    unsigned short* A_dec= (unsigned short*)(W + 53510144); // 1152x512x2  = 1,179,648
    float* b_enc         = (float*)(W + 54689792);          // 512 f
    float* b_lay         = (float*)(W + 54691840);          // 2048 f
    float* b_dec         = (float*)(W + 54700032);          // 1028 f

    // ---- d_out doubles as scratch ----
    unsigned short* y   = (unsigned short*)((uint8_t*)d_out + 33554432);   // 16,777,216
    unsigned short* xp  = (unsigned short*)d_out;  // 34,603,008; dead after encoder GEMM

    // ---- build all weights/biases in one launch ----
    buildall_k<<<8527, 256, 0, stream>>>(enc_Wr, enc_Wi, out_Wr, out_Wi,
                                         dec_Wr, dec_Wi, enc_br, enc_bi,
                                         out_br, out_bi, dec_br, dec_bi,
                                         A_enc, A_lay, A_dec,
                                         b_enc, b_lay, b_dec);

    // ---- encoder: pack x -> xp, GEMM -> z ----
    packx_k<<<dim3(32, 9, 8), 256, 0, stream>>>(x, xp);
    mgemm_k<<<dim3(4, 16, 8), 256, 0, stream>>>(A_enc, b_enc, xp, z, 512, 1056);

    // ---- layers: scan -> fused transpose+GEMM+residual+LN ----
    for (int l = 0; l < 4; ++l) {
        s4scan_k<<<dim3(256, 8), 256, 0, stream>>>(z, y, log_dt, log_A_r, A_imag, C_r, C_i, Dp, l);
        mgemmln_k<<<dim3(32, 8), 512, 0, stream>>>(A_lay + (size_t)l * 262144,
                                                   b_lay + l * 512, y, z,
                                                   ln_gr, ln_gi, ln_br, ln_bi, l);
    }

    // ---- decoder: fused transpose+convert+GEMM -> d_out paired stores ----
    mgemmdec_k<<<dim3(3, 32, 8), 512, 0, stream>>>(A_dec, b_dec, z, (float*)d_out);
}